// Round 1
// baseline (2818.902 us; speedup 1.0000x reference)
//
#include <hip/hip_runtime.h>
#include <hip/hip_bf16.h>

typedef _Float16 f16x2 __attribute__((ext_vector_type(2)));

#define HID 300
#define NSEQ 64
#define NROWS 4096   // B*N = 64*64

union U { uint4 u; f16x2 h[4]; };

__device__ __forceinline__ float sigm(float x){ return 1.f/(1.f+__expf(-x)); }

__device__ __forceinline__ float fdot2a(f16x2 a, f16x2 b, float c){
#if __has_builtin(__builtin_amdgcn_fdot2)
  return __builtin_amdgcn_fdot2(a, b, c, false);
#else
  return c + (float)a.x*(float)b.x + (float)a.y*(float)b.y;
#endif
}

// Relaxed agent-scope ops: LLC-coherent, NO cache maintenance (no L2 flush).
__device__ __forceinline__ void xstore(float* p, float v){
  __hip_atomic_store(p, v, __ATOMIC_RELAXED, __HIP_MEMORY_SCOPE_AGENT);
}
__device__ __forceinline__ float xload(const float* p){
  return __hip_atomic_load(p, __ATOMIC_RELAXED, __HIP_MEMORY_SCOPE_AGENT);
}

// ---------------------------------------------------------------------------
// Merged repack: f32 -> fp16 pairs, [kg][outs][4 pairs] coalesced; also zeroes
// the pipeline sync counters + claim pools every launch.
// ---------------------------------------------------------------------------
__global__ void convert_all_kernel(
    const float* __restrict__ whh_c, const float* __restrict__ wih_p,
    const float* __restrict__ wih_c, const float* __restrict__ whh_p,
    const float* __restrict__ wr0,   const float* __restrict__ wr1,
    const float* __restrict__ w_in,  const float* __restrict__ w1,
    const float* __restrict__ w2,
    f16x2* __restrict__ W_M4, f16x2* __restrict__ WrT4, f16x2* __restrict__ W_P4,
    f16x2* __restrict__ W_H4, f16x2* __restrict__ W_14, f16x2* __restrict__ W_24,
    int* __restrict__ syncc)
{
  const int NA = 4*38*1800*4;
  const int NB = 4*38*600*4;
  const int NP = 4*38*1800*4;
  const int NH = 128*300*4;
  const int N1 = 318*304*4;
  const int N2 = 38*304*4;
  const int NS = 3*32*16 + 64;   // step counters (3 layers x 32 pairs) + claim pools
  const int TOT = NA+NB+NP+NH+N1+N2+NS;
  for (int idx0 = blockIdx.x*blockDim.x + threadIdx.x; idx0 < TOT; idx0 += gridDim.x*blockDim.x){
    int idx = idx0;
    if (idx < NA){
      int l    = idx/(38*1800*4);
      int rem  = idx - l*(38*1800*4);
      int kg   = rem/(1800*4);
      int rem2 = rem - kg*(1800*4);
      int o = rem2>>2, s = rem2&3;
      int c = (kg*4+s)*2;
      float v0=0.f, v1=0.f;
      if (c < 300){
        const float* src = (o<900) ? (whh_c + ((size_t)l*900+o)*300)
                                   : (wih_p + ((size_t)l*900+(o-900))*300);
        v0 = src[c]; v1 = src[c+1];
      }
      f16x2 t; t.x=(_Float16)v0; t.y=(_Float16)v1;
      W_M4[idx] = t; continue;
    }
    idx -= NA;
    if (idx < NB){
      int l    = idx/(38*600*4);
      int rem  = idx - l*(38*600*4);
      int kg   = rem/(600*4);
      int rem2 = rem - kg*(600*4);
      int t6 = rem2>>2, s = rem2&3;
      int d = t6>>1, hh = t6&1;
      int c = (kg*4+s)*2;
      float v0=0.f, v1=0.f;
      if (c < 300){
        const float* src = hh ? (wr1 + ((size_t)l*300+d)*300)
                              : (wr0 + ((size_t)l*300+d)*300);
        v0 = src[c]; v1 = src[c+1];
      }
      f16x2 t; t.x=(_Float16)v0; t.y=(_Float16)v1;
      WrT4[idx] = t; continue;
    }
    idx -= NB;
    if (idx < NP){
      int l    = idx/(38*1800*4);
      int rem  = idx - l*(38*1800*4);
      int kg   = rem/(1800*4);
      int rem2 = rem - kg*(1800*4);
      int o = rem2>>2, s = rem2&3;
      int c = (kg*4+s)*2;
      float v0=0.f, v1=0.f;
      if (c < 300){
        const float* src = (o<900) ? (wih_c + ((size_t)l*900+o)*300)
                                   : (whh_p + ((size_t)l*900+(o-900))*300);
        v0 = src[c]; v1 = src[c+1];
      }
      f16x2 t; t.x=(_Float16)v0; t.y=(_Float16)v1;
      W_P4[idx] = t; continue;
    }
    idx -= NP;
    if (idx < NH){
      int kg  = idx/(300*4);
      int rem = idx - kg*(300*4);
      int o = rem>>2, s = rem&3;
      int c = (kg*4+s)*2;
      f16x2 t; t.x=(_Float16)w_in[(size_t)o*1024+c]; t.y=(_Float16)w_in[(size_t)o*1024+c+1];
      W_H4[idx] = t; continue;
    }
    idx -= NH;
    if (idx < N1){
      int kgg = idx/(304*4);
      int rem = idx - kgg*(304*4);
      int o = rem>>2, s = rem&3;
      int segbase, seglen, kgl;
      if (kgg < 190){ int seg = kgg/38; kgl = kgg - seg*38; segbase = seg*300; seglen = 300; }
      else { int kk = kgg-190; int sf = kk>>6; kgl = kk&63; segbase = 1500 + sf*512; seglen = 512; }
      int c = (kgl*4+s)*2;
      float v0=0.f, v1=0.f;
      if (o < 300 && c < seglen){
        v0 = w1[(size_t)o*2524 + segbase + c];
        if (c+1 < seglen) v1 = w1[(size_t)o*2524 + segbase + c + 1];
      }
      f16x2 t; t.x=(_Float16)v0; t.y=(_Float16)v1;
      W_14[idx] = t; continue;
    }
    idx -= N1;
    if (idx < N2){
      int kg = idx/(304*4);
      int rem = idx - kg*(304*4);
      int o = rem>>2, s = rem&3;
      int c = (kg*4+s)*2;
      float v0=0.f, v1=0.f;
      if (o < 300 && c < 300){ v0 = w2[(size_t)o*300+c]; v1 = w2[(size_t)o*300+c+1]; }
      f16x2 t; t.x=(_Float16)v0; t.y=(_Float16)v1;
      W_24[idx] = t; continue;
    }
    idx -= N2;
    syncc[idx] = 0;
  }
}

// ---------------------------------------------------------------------------
// H0 = relu(features @ w_in^T + b_in), coalesced fp16 weights.
// ---------------------------------------------------------------------------
__global__ __launch_bounds__(256) void h0_kernel(const float* __restrict__ feat,
    const f16x2* __restrict__ WH, const float* __restrict__ b_in, float* __restrict__ H0)
{
  const int tid = threadIdx.x;
  const int r0  = blockIdx.x*8;
  __shared__ f16x2 X[8][512];
  for (int t=tid; t<8*512; t+=256){
    int r=t>>9, p=t&511, c=2*p;
    f16x2 h; h.x=(_Float16)feat[(size_t)(r0+r)*1024+c];
    h.y=(_Float16)feat[(size_t)(r0+r)*1024+c+1];
    X[r][p]=h;
  }
  __syncthreads();
  const uint4* WHu = (const uint4*)WH;
  const int o0 = tid, o1 = tid+256;
  const bool h1v = (o1 < 300);
  float acc[2][8];
  #pragma unroll
  for (int j=0;j<2;j++)
    #pragma unroll
    for (int r=0;r<8;r++) acc[j][r]=0.f;
  for (int kg=0; kg<128; kg++){
    U w0, w1;
    w0.u = WHu[(size_t)kg*300 + o0];
    if (h1v) w1.u = WHu[(size_t)kg*300 + o1];
    #pragma unroll
    for (int r=0;r<8;r++){
      const f16x2* xp = &X[r][kg*4];
      f16x2 x0=xp[0],x1=xp[1],x2=xp[2],x3=xp[3];
      acc[0][r] = fdot2a(w0.h[3],x3, fdot2a(w0.h[2],x2, fdot2a(w0.h[1],x1, fdot2a(w0.h[0],x0, acc[0][r]))));
      if (h1v)
        acc[1][r] = fdot2a(w1.h[3],x3, fdot2a(w1.h[2],x2, fdot2a(w1.h[1],x1, fdot2a(w1.h[0],x0, acc[1][r]))));
    }
  }
  {
    float bb = b_in[o0];
    #pragma unroll
    for (int r=0;r<8;r++) H0[(size_t)(r0+r)*HID + o0] = fmaxf(acc[0][r]+bb, 0.f);
  }
  if (h1v){
    float bb = b_in[o1];
    #pragma unroll
    for (int r=0;r<8;r++) H0[(size_t)(r0+r)*HID + o1] = fmaxf(acc[1][r]+bb, 0.f);
  }
}

// ---------------------------------------------------------------------------
// Fused 4-layer pipelined scan, 2 CHAINS PER WG: 128 WGs = 4 layers x 32 pairs.
// This round: __launch_bounds__(1024,4) frees VGPRs to 128 (LDS already caps
// us at 1 WG/CU); all three kg matvec loops get explicit depth-2 weight
// prefetch; softmax's q-term removed (shift-invariant: q_i and gb cancel),
// so A folds into F of the previous step and B folds into the P phase.
// ---------------------------------------------------------------------------
__global__ __launch_bounds__(1024, 4) void scan_pipe_kernel(
  float* __restrict__ Hball,
  const f16x2* __restrict__ W_M4, const f16x2* __restrict__ WrT4, const f16x2* __restrict__ W_P4,
  const float* __restrict__ bih_c, const float* __restrict__ bhh_c,
  const float* __restrict__ bih_p, const float* __restrict__ bhh_p,
  const float* __restrict__ gwq, const float* __restrict__ gwk, const float* __restrict__ gbv,
  const int* __restrict__ speakers, float* __restrict__ xrow, int* __restrict__ syncc)
{
  (void)gwq; (void)gbv;   // softmax is shift-invariant: q and b cancel exactly
  __shared__ _Float16 Hh[2][NSEQ][304];
  __shared__ float pre_s[2][1800];
  __shared__ float gates[2][1800];
  __shared__ float Mf[2][304];
  __shared__ f16x2 Mh[2][152];
  __shared__ f16x2 u01h[2][304];
  __shared__ float wgt[2][NSEQ];
  __shared__ float kd[2][NSEQ];
  __shared__ float red[2][320];
  __shared__ float xf[2][304];
  __shared__ f16x2 xh[2][152];
  __shared__ int   spk[2][NSEQ];
  __shared__ int   startA[2][NSEQ];
  __shared__ int   sLayer, sPair;

  const int tid = threadIdx.x;

  // --- claim (layer, pair) with XCD-local preference ---
  if (tid == 0){
    int xcc = 0;
    asm volatile("s_getreg_b32 %0, hwreg(HW_REG_XCC_ID)" : "=s"(xcc));
    int pref = (xcc >> 1) & 3;
    int* claimc = syncc + 3*32*16;
    int l = 0, p = 0;
    #pragma unroll 1
    for (int t=0; t<4; ++t){
      int cand = (pref + t) & 3;
      int idx = __hip_atomic_fetch_add(&claimc[cand*16], 1, __ATOMIC_RELAXED, __HIP_MEMORY_SCOPE_AGENT);
      if (idx < 32){ l = cand; p = idx; break; }
    }
    sLayer = l; sPair = p;
  }
  __syncthreads();
  const int layer = __builtin_amdgcn_readfirstlane(sLayer);
  const int pair  = __builtin_amdgcn_readfirstlane(sPair);
  const int base0 = (2*pair)*NSEQ;
  const int base1 = (2*pair+1)*NSEQ;

  const uint4* Wm4 = (const uint4*)(W_M4 + (size_t)layer*38*1800*4);
  const uint4* Wr4 = (const uint4*)(WrT4 + (size_t)layer*38*600*4);
  const uint4* Wp4 = (const uint4*)(W_P4 + (size_t)layer*38*1800*4);
  const float* HinB0 = Hball + (size_t)base0*300;
  const float* HinB1 = Hball + (size_t)base1*300;
  float* HoutB0 = Hball + ((size_t)(layer+1)*NROWS + (size_t)base0)*300;
  float* HoutB1 = Hball + ((size_t)(layer+1)*NROWS + (size_t)base1)*300;
  int* cntP = syncc + (layer*32 + pair)*16;
  int* cntC = (layer>0) ? (syncc + ((layer-1)*32 + pair)*16) : (int*)0;
  const float* xin  = xrow + (size_t)(((layer-1)*32 + pair)*2)*NSEQ*300;  // layer>0
  float*       xout = xrow + (size_t)((layer*32 + pair)*2)*NSEQ*300;      // layer<3

  const int w  = tid >> 6;     // wave id 0..15
  const int rc = tid >> 9;     // half 0/1 (chain for R/E phases)
  const int rt = tid & 511;

  // step-invariant per-thread regs (same for both halves)
  float bcr=0,bcz=0,bcn=0,bpr=0,bpz=0,bpn=0,wkv=0;
  if (rt < 300){
    bcr=bhh_c[layer*900+rt]; bcz=bhh_c[layer*900+300+rt]; bcn=bhh_c[layer*900+600+rt];
    bpr=bih_p[layer*900+rt]; bpz=bih_p[layer*900+300+rt]; bpn=bih_p[layer*900+600+rt];
    wkv=gwk[layer*300+rt];
  }

  // P/D output mapping: o1 = tid, o2 = tid+1024 (776 threads do 2 outputs)
  const int o1 = tid, o2 = tid+1024;
  const bool dhas2 = (o2 < 1800);
  float ppb1 = (o1<900) ? bih_c[layer*900+o1] : bhh_p[layer*900+o1-900];
  float ppb2 = 0.f;
  if (dhas2) ppb2 = (o2<900) ? bih_c[layer*900+o2] : bhh_p[layer*900+o2-900];

  // init
  if (tid < 64) spk[0][tid] = speakers[base0+tid];
  else if (tid < 128) spk[1][tid-64] = speakers[base1+(tid-64)];
  for (int t=tid; t<2*1800; t+=1024) ((float*)gates)[t]=0.f;
  for (int t=tid; t<2*304; t+=1024) ((float*)Mf)[t]=0.f;
  if (tid >= 128 && tid < 168){ int t=tid-128; red[t/20][300+(t%20)] = 0.f; }
  if (tid >= 168 && tid < 176){ int t=tid-168; xf[t>>2][300+(t&3)] = 0.f; }
  if (tid >= 176 && tid < 180){
    int t=tid-176; f16x2 z; z.x=(_Float16)0.f; z.y=(_Float16)0.f;
    Mh[t>>1][150+(t&1)]=z; xh[t>>1][150+(t&1)]=z;
    u01h[t>>1][150+(t&1)]=z; u01h[t>>1][302+(t&1)]=z;
  }
  __syncthreads();
  if (tid < 64){
    int s=0; for (int j=tid-1;j>=0;--j) if (spk[0][j]==spk[0][tid]){s=j;break;}
    startA[0][tid]=s;
  } else if (tid < 128){
    int t=tid-64;
    int s=0; for (int j=t-1;j>=0;--j) if (spk[1][j]==spk[1][t]){s=j;break;}
    startA[1][t]=s;
  }
  if (layer>0 && tid==0){
    while (__hip_atomic_load(cntC, __ATOMIC_RELAXED, __HIP_MEMORY_SCOPE_AGENT) < 1)
      __builtin_amdgcn_s_sleep(8);
  }
  __syncthreads();

  #pragma unroll 1
  for (int i=0; i<NSEQ; ++i){
    // R: receive/load input row i for both chains
    if (rt < 150){
      float x0, x1;
      if (layer==0){
        const float* Hin = rc ? HinB1 : HinB0;
        float2 v = *(const float2*)(Hin + (size_t)i*300 + 2*rt);
        x0=v.x; x1=v.y;
      } else {
        const float* xi = xin + (size_t)rc*NSEQ*300 + (size_t)i*300;
        x0 = xload(xi + 2*rt);
        x1 = xload(xi + 2*rt + 1);
      }
      xf[rc][2*rt]=x0; xf[rc][2*rt+1]=x1;
      f16x2 h; h.x=(_Float16)x0; h.y=(_Float16)x1; xh[rc][rt]=h;
    }
    __syncthreads();

    // P phase (all 1024 threads) with depth-2 prefetch; B tasks hidden behind
    // the first weight loads (B depends only on prev-step wgt/Hh).
    {
      U pa0, pa1, pb0, pb1v;
      pa0.u = Wp4[o1];
      pb0.u = Wp4[1800 + o1];
      if (dhas2){ pa1.u = Wp4[o2]; pb1v.u = Wp4[1800 + o2]; }

      if (i > 0){
        #pragma unroll 1
        for (int pass=0; pass<2; ++pass){
          int T = tid + pass*1024;
          if (T < 1200){
            const int c = (T >= 600);
            const int t = T - c*600;
            const int d  = (t<300)? t : (t-300);
            const int wh = (t>=300);
            const int st = startA[c][i]; const int ms = spk[c][i];
            float u=0.f;
            for (int j=st;j<i;++j){
              float sel = ((spk[c][j]==ms) != (wh!=0)) ? 1.f : 0.f;
              u += sel*wgt[c][j]*(float)Hh[c][j][d];
            }
            ((_Float16*)&u01h[c][0])[(wh?304:0) + d] = (_Float16)u;
          }
        }
      }

      float aA0=0,aA1=0,aA2=0,aA3=0, aB0=0,aB1=0,aB2=0,aB3=0;
      float eA0=0,eA1=0,eA2=0,eA3=0, eB0=0,eB1=0,eB2=0,eB3=0;
      #pragma unroll 1
      for (int kg=0; kg<38; kg+=2){
        U c0 = pa0, c1 = pa1;
        if (kg+2 < 38){
          pa0.u = Wp4[(size_t)(kg+2)*1800 + o1];
          if (dhas2) pa1.u = Wp4[(size_t)(kg+2)*1800 + o2];
        }
        {
          f16x2 xA0=xh[0][kg*4+0],xA1=xh[0][kg*4+1],xA2=xh[0][kg*4+2],xA3=xh[0][kg*4+3];
          f16x2 xB0=xh[1][kg*4+0],xB1=xh[1][kg*4+1],xB2=xh[1][kg*4+2],xB3=xh[1][kg*4+3];
          aA0=fdot2a(c0.h[0],xA0,aA0); aA1=fdot2a(c0.h[1],xA1,aA1);
          aA2=fdot2a(c0.h[2],xA2,aA2); aA3=fdot2a(c0.h[3],xA3,aA3);
          aB0=fdot2a(c0.h[0],xB0,aB0); aB1=fdot2a(c0.h[1],xB1,aB1);
          aB2=fdot2a(c0.h[2],xB2,aB2); aB3=fdot2a(c0.h[3],xB3,aB3);
          if (dhas2){
            eA0=fdot2a(c1.h[0],xA0,eA0); eA1=fdot2a(c1.h[1],xA1,eA1);
            eA2=fdot2a(c1.h[2],xA2,eA2); eA3=fdot2a(c1.h[3],xA3,eA3);
            eB0=fdot2a(c1.h[0],xB0,eB0); eB1=fdot2a(c1.h[1],xB1,eB1);
            eB2=fdot2a(c1.h[2],xB2,eB2); eB3=fdot2a(c1.h[3],xB3,eB3);
          }
        }
        U d0 = pb0, d1 = pb1v;
        if (kg+3 < 38){
          pb0.u = Wp4[(size_t)(kg+3)*1800 + o1];
          if (dhas2) pb1v.u = Wp4[(size_t)(kg+3)*1800 + o2];
        }
        {
          f16x2 xA0=xh[0][(kg+1)*4+0],xA1=xh[0][(kg+1)*4+1],xA2=xh[0][(kg+1)*4+2],xA3=xh[0][(kg+1)*4+3];
          f16x2 xB0=xh[1][(kg+1)*4+0],xB1=xh[1][(kg+1)*4+1],xB2=xh[1][(kg+1)*4+2],xB3=xh[1][(kg+1)*4+3];
          aA0=fdot2a(d0.h[0],xA0,aA0); aA1=fdot2a(d0.h[1],xA1,aA1);
          aA2=fdot2a(d0.h[2],xA2,aA2); aA3=fdot2a(d0.h[3],xA3,aA3);
          aB0=fdot2a(d0.h[0],xB0,aB0); aB1=fdot2a(d0.h[1],xB1,aB1);
          aB2=fdot2a(d0.h[2],xB2,aB2); aB3=fdot2a(d0.h[3],xB3,aB3);
          if (dhas2){
            eA0=fdot2a(d1.h[0],xA0,eA0); eA1=fdot2a(d1.h[1],xA1,eA1);
            eA2=fdot2a(d1.h[2],xA2,eA2); eA3=fdot2a(d1.h[3],xA3,eA3);
            eB0=fdot2a(d1.h[0],xB0,eB0); eB1=fdot2a(d1.h[1],xB1,eB1);
            eB2=fdot2a(d1.h[2],xB2,eB2); eB3=fdot2a(d1.h[3],xB3,eB3);
          }
        }
      }
      pre_s[0][o1] = (aA0+aA1)+(aA2+aA3) + ppb1;
      pre_s[1][o1] = (aB0+aB1)+(aB2+aB3) + ppb1;
      if (dhas2){
        pre_s[0][o2] = (eA0+eA1)+(eA2+eA3) + ppb2;
        pre_s[1][o2] = (eB0+eB1)+(eB2+eB3) + ppb2;
      }
    }
    __syncthreads();

    if (i > 0){
      // C: M = wr0@u0 + wr1@u1, both chains per weight load, depth-2 prefetch
      if (tid < 600){
        const int hh = tid&1;
        const f16x2* uA = (const f16x2*)&u01h[0][0] + hh*152;
        const f16x2* uB = (const f16x2*)&u01h[1][0] + hh*152;
        U v0, v1;
        v0.u = Wr4[o1];
        v1.u = Wr4[600 + o1];
        float a0=0,a1=0,a2=0,a3=0, b0=0,b1=0,b2=0,b3=0;
        #pragma unroll 1
        for (int kg=0; kg<38; kg+=2){
          U c0 = v0;
          if (kg+2<38) v0.u = Wr4[(size_t)(kg+2)*600 + o1];
          a0=fdot2a(c0.h[0],uA[kg*4+0],a0); a1=fdot2a(c0.h[1],uA[kg*4+1],a1);
          a2=fdot2a(c0.h[2],uA[kg*4+2],a2); a3=fdot2a(c0.h[3],uA[kg*4+3],a3);
          b0=fdot2a(c0.h[0],uB[kg*4+0],b0); b1=fdot2a(c0.h[1],uB[kg*4+1],b1);
          b2=fdot2a(c0.h[2],uB[kg*4+2],b2); b3=fdot2a(c0.h[3],uB[kg*4+3],b3);
          U c1 = v1;
          if (kg+3<38) v1.u = Wr4[(size_t)(kg+3)*600 + o1];
          a0=fdot2a(c1.h[0],uA[(kg+1)*4+0],a0); a1=fdot2a(c1.h[1],uA[(kg+1)*4+1],a1);
          a2=fdot2a(c1.h[2],uA[(kg+1)*4+2],a2); a3=fdot2a(c1.h[3],uA[(kg+1)*4+3],a3);
          b0=fdot2a(c1.h[0],uB[(kg+1)*4+0],b0); b1=fdot2a(c1.h[1],uB[(kg+1)*4+1],b1);
          b2=fdot2a(c1.h[2],uB[(kg+1)*4+2],b2); b3=fdot2a(c1.h[3],uB[(kg+1)*4+3],b3);
        }
        float aA = (a0+a1)+(a2+a3);
        float aB = (b0+b1)+(b2+b3);
        float m2A = aA + __shfl_xor(aA,1);
        float m2B = aB + __shfl_xor(aB,1);
        if ((tid&1)==0){ Mf[0][tid>>1] = m2A; Mf[1][tid>>1] = m2B; }
        float moA = __shfl_xor(m2A,2);
        float moB = __shfl_xor(m2B,2);
        if ((tid&3)==0){
          f16x2 hA; hA.x=(_Float16)m2A; hA.y=(_Float16)moA; Mh[0][tid>>2]=hA;
          f16x2 hB; hB.x=(_Float16)m2B; hB.y=(_Float16)moB; Mh[1][tid>>2]=hB;
        }
      }
      __syncthreads();
      // D: gates = [whh_c ; wih_p] @ M, both chains per weight load, prefetch
      {
        U va0, va1, vb0, vb1;
        va0.u = Wm4[o1];
        vb0.u = Wm4[1800 + o1];
        if (dhas2){ va1.u = Wm4[o2]; vb1.u = Wm4[1800 + o2]; }
        float aA0=0,aA1=0,aA2=0,aA3=0, aB0=0,aB1=0,aB2=0,aB3=0;
        float eA0=0,eA1=0,eA2=0,eA3=0, eB0=0,eB1=0,eB2=0,eB3=0;
        #pragma unroll 1
        for (int kg=0; kg<38; kg+=2){
          U c0 = va0, c1 = va1;
          if (kg+2<38){
            va0.u = Wm4[(size_t)(kg+2)*1800 + o1];
            if (dhas2) va1.u = Wm4[(size_t)(kg+2)*1800 + o2];
          }
          {
            f16x2 mA0=Mh[0][kg*4+0], mA1=Mh[0][kg*4+1], mA2=Mh[0][kg*4+2], mA3=Mh[0][kg*4+3];
            f16x2 mB0=Mh[1][kg*4+0], mB1=Mh[1][kg*4+1], mB2=Mh[1][kg*4+2], mB3=Mh[1][kg*4+3];
            aA0=fdot2a(c0.h[0],mA0,aA0); aA1=fdot2a(c0.h[1],mA1,aA1);
            aA2=fdot2a(c0.h[2],mA2,aA2); aA3=fdot2a(c0.h[3],mA3,aA3);
            aB0=fdot2a(c0.h[0],mB0,aB0); aB1=fdot2a(c0.h[1],mB1,aB1);
            aB2=fdot2a(c0.h[2],mB2,aB2); aB3=fdot2a(c0.h[3],mB3,aB3);
            if (dhas2){
              eA0=fdot2a(c1.h[0],mA0,eA0); eA1=fdot2a(c1.h[1],mA1,eA1);
              eA2=fdot2a(c1.h[2],mA2,eA2); eA3=fdot2a(c1.h[3],mA3,eA3);
              eB0=fdot2a(c1.h[0],mB0,eB0); eB1=fdot2a(c1.h[1],mB1,eB1);
              eB2=fdot2a(c1.h[2],mB2,eB2); eB3=fdot2a(c1.h[3],mB3,eB3);
            }
          }
          U d0 = vb0, d1 = vb1;
          if (kg+3<38){
            vb0.u = Wm4[(size_t)(kg+3)*1800 + o1];
            if (dhas2) vb1.u = Wm4[(size_t)(kg+3)*1800 + o2];
          }
          {
            f16x2 mA0=Mh[0][(kg+1)*4+0], mA1=Mh[0][(kg+1)*4+1], mA2=Mh[0][(kg+1)*4+2], mA3=Mh[0][(kg+1)*4+3];
            f16x2 mB0=Mh[1][(kg+1)*4+0], mB1=Mh[1][(kg+1)*4+1], mB2=Mh[1][(kg+1)*4+2], mB3=Mh[1][(kg+1)*4+3];
            aA0=fdot2a(d0.h[0],mA0,aA0); aA1=fdot2a(d0.h[1],mA1,aA1);
            aA2=fdot2a(d0.h[2],mA2,aA2); aA3=fdot2a(d0.h[3],mA3,aA3);
            aB0=fdot2a(d0.h[0],mB0,aB0); aB1=fdot2a(d0.h[1],mB1,aB1);
            aB2=fdot2a(d0.h[2],mB2,aB2); aB3=fdot2a(d0.h[3],mB3,aB3);
            if (dhas2){
              eA0=fdot2a(d1.h[0],mA0,eA0); eA1=fdot2a(d1.h[1],mA1,eA1);
              eA2=fdot2a(d1.h[2],mA2,eA2); eA3=fdot2a(d1.h[3],mA3,eA3);
              eB0=fdot2a(d1.h[0],mB0,eB0); eB1=fdot2a(d1.h[1],mB1,eB1);
              eB2=fdot2a(d1.h[2],mB2,eB2); eB3=fdot2a(d1.h[3],mB3,eB3);
            }
          }
        }
        gates[0][o1] = (aA0+aA1)+(aA2+aA3);
        gates[1][o1] = (aB0+aB1)+(aB2+aB3);
        if (dhas2){
          gates[0][o2] = (eA0+eA1)+(eA2+eA3);
          gates[1][o2] = (eB0+eB1)+(eB2+eB3);
        }
      }
      __syncthreads();
    }
    // E: GRU combine for chain rc on thread-halves
    if (rt < 300){
      const float M = Mf[rc][rt];
      const float* ps = pre_s[rc];
      const float* gs = gates[rc];
      float r  = sigm(ps[rt] + gs[rt] + bcr);
      float z  = sigm(ps[300+rt] + gs[300+rt] + bcz);
      float n  = tanhf(ps[600+rt] + r*(gs[600+rt]+bcn));
      float C  = (1.f-z)*n + z*M;
      float rp = sigm(gs[900+rt]+bpr + ps[900+rt]);
      float zp = sigm(gs[1200+rt]+bpz + ps[1200+rt]);
      float np = tanhf(gs[1500+rt]+bpn + rp*ps[1500+rt]);
      float qv = xf[rc][rt];
      float P  = (1.f-zp)*np + zp*qv;
      float h  = C + P;
      float* Ho = rc ? HoutB1 : HoutB0;
      Ho[(size_t)i*300 + rt] = h;
      Hh[rc][i][rt] = (_Float16)h;
      red[rc][rt] = h*wkv;
      if (layer<3) xstore(xout + (size_t)rc*NSEQ*300 + (size_t)i*300 + rt, h);
    }
    asm volatile("s_waitcnt vmcnt(0)" ::: "memory");   // drain publish before counting
    __syncthreads();
    // F: kd[c][i] reduce + A(i+1) softmax (q & b cancel) on waves 0,8;
    //    counter bump + poll on tid 0
    if (w==0 || w==8){
      const int c = (w==8);
      const int lane = tid & 63;
      float s = red[c][lane]+red[c][lane+64]+red[c][lane+128]+red[c][lane+192]+red[c][lane+256];
      #pragma unroll
      for (int o=32;o>0;o>>=1) s += __shfl_xor(s,o);
      if (lane==0) kd[c][i]=s;
      if (i+1 < NSEQ){
        const int st = startA[c][i+1];
        const bool in = (lane>=st) && (lane<=i);
        float kv = (lane==i) ? s : kd[c][lane];
        float a = in ? kv : -3.0e38f;
        float m = a;
        #pragma unroll
        for (int o=32;o>0;o>>=1) m = fmaxf(m,__shfl_xor(m,o));
        float e = in ? __expf(a-m) : 0.f;
        float ss = e;
        #pragma unroll
        for (int o=32;o>0;o>>=1) ss += __shfl_xor(ss,o);
        wgt[c][lane] = e/ss;
      }
    }
    if (tid==0){
      if (layer<3) __hip_atomic_fetch_add(cntP, 1, __ATOMIC_RELAXED, __HIP_MEMORY_SCOPE_AGENT);
      if (layer>0 && i<63){
        while (__hip_atomic_load(cntC, __ATOMIC_RELAXED, __HIP_MEMORY_SCOPE_AGENT) < i+2)
          __builtin_amdgcn_s_sleep(2);
      }
    }
    __syncthreads();
  }
}

// ---------------------------------------------------------------------------
// Head with fp16-dot2 GEMMs (unchanged).
// ---------------------------------------------------------------------------
__global__ __launch_bounds__(256) void head_kernel(
  const float* __restrict__ H0, const float* __restrict__ Hl1,
  const float* __restrict__ Hl2, const float* __restrict__ Hl3,
  const float* __restrict__ Hl4, const float* __restrict__ feat,
  const f16x2* __restrict__ W14, const float* __restrict__ b1,
  const f16x2* __restrict__ W24, const float* __restrict__ b2,
  const float* __restrict__ w3, const float* __restrict__ b3,
  float* __restrict__ out)
{
  const int tid = threadIdx.x;
  const int r0  = blockIdx.x*16;
  __shared__ f16x2 Xh[16*256];
  __shared__ _Float16 h1h[16*304];
  __shared__ float S2[16*304];
  const uint4* W14u = (const uint4*)W14;
  const uint4* W24u = (const uint4*)W24;

  float acc0[16], acc1[16];
  #pragma unroll
  for (int r=0;r<16;r++){ acc0[r]=0.f; acc1[r]=0.f; }
  const int o  = tid;
  const int o2 = tid + 256;
  const bool has2 = (o2 < 300);

  #pragma unroll
  for (int seg=0; seg<7; seg++){
    const float* src = (seg==0)?H0:(seg==1)?Hl1:(seg==2)?Hl2:(seg==3)?Hl3:(seg==4)?Hl4:feat;
    if (seg < 5){
      for (int t=tid; t<16*152; t+=256){
        int r=t/152, p=t-r*152, c=2*p;
        float v0 = (c<300)? src[(size_t)(r0+r)*300 + c] : 0.f;
        float v1 = (c+1<300)? src[(size_t)(r0+r)*300 + c+1] : 0.f;
        f16x2 h; h.x=(_Float16)v0; h.y=(_Float16)v1;
        Xh[r*256+p] = h;
      }
    } else {
      const int cb = (seg-5)*512;
      for (int t=tid; t<16*256; t+=256){
        int r=t>>8, p=t&255;
        float v0 = src[(size_t)(r0+r)*1024 + cb + 2*p];
        float v1 = src[(size_t)(r0+r)*1024 + cb + 2*p+1];
        f16x2 h; h.x=(_Float16)v0; h.y=(_Float16)v1;
        Xh[r*256+p] = h;
      }
    }
    __syncthreads();
    const int kgs = (seg<5)?38:64;
    const int kgo = (seg<5)? seg*38 : 190+(seg-5)*64;
    if (o < 300){
      for (int kg=0; kg<kgs; kg++){
        U a, b;
        a.u = W14u[(size_t)(kgo+kg)*304 + o];
        if (has2) b.u = W14u[(size_t)(kgo+kg)*304 + o2];
        #pragma unroll
        for (int r=0;r<16;r++){
          const f16x2* xp = &Xh[r*256 + kg*4];
          float t0 = fdot2a(a.h[0], xp[0], 0.f);
          t0 = fdot2a(a.h[1], xp[1], t0);
          t0 = fdot2a(a.h[2], xp[2], t0);
          t0 = fdot2a(a.h[3], xp[3], t0);
          acc0[r] += t0;
          if (has2){
            float t1 = fdot2a(b.h[0], xp[0], 0.f);
            t1 = fdot2a(b.h[1], xp[1], t1);
            t1 = fdot2a(b.h[2], xp[2], t1);
            t1 = fdot2a(b.h[3], xp[3], t1);
            acc1[r] += t1;
          }
        }
      }
    }
    __syncthreads();
  }
  if (o < 300){
    float bb = b1[o];
    #pragma unroll
    for (int r=0;r<16;r++) h1h[r*304+o] = (_Float16)fmaxf(acc0[r]+bb, 0.f);
  }
  if (has2){
    float bb = b1[o2];
    #pragma unroll
    for (int r=0;r<16;r++) h1h[r*304+o2] = (_Float16)fmaxf(acc1[r]+bb, 0.f);
  }
  if (tid < 4){
    #pragma unroll
    for (int r=0;r<16;r++) h1h[r*304+300+tid] = (_Float16)0.f;
  }
  __syncthreads();
  #pragma unroll
  for (int r=0;r<16;r++){ acc0[r]=0.f; acc1[r]=0.f; }
  if (o < 300){
    for (int kg=0; kg<38; kg++){
      U a, b;
      a.u = W24u[(size_t)kg*304 + o];
      if (has2) b.u = W24u[(size_t)kg*304 + o2];
      #pragma unroll
      for (int r=0;r<16;r++){
        const f16x2* xp = (const f16x2*)&h1h[r*304] + kg*4;
        float t0 = fdot2a(a.h[0], xp[0], 0.f);
        t0 = fdot2a(a.h[1], xp[1], t0);
        t0 = fdot2a(a.h[2], xp[2], t0);
        t0 = fdot2a(a.h[3], xp[3], t0);
        acc0[r] += t0;
        if (has2){
          float t1 = fdot2a(b.h[0], xp[0], 0.f);
          t1 = fdot2a(b.h[1], xp[1], t1);
          t1 = fdot2a(b.h[2], xp[2], t1);
          t1 = fdot2a(b.h[3], xp[3], t1);
          acc1[r] += t1;
        }
      }
    }
  }
  __syncthreads();
  if (o < 300){
    float bb = b2[o];
    #pragma unroll
    for (int r=0;r<16;r++) S2[r*304+o] = fmaxf(acc0[r]+bb, 0.f);
  }
  if (has2){
    float bb = b2[o2];
    #pragma unroll
    for (int r=0;r<16;r++) S2[r*304+o2] = fmaxf(acc1[r]+bb, 0.f);
  }
  __syncthreads();
  if (tid < 16*7){
    int r = tid/7, c = tid - r*7;
    float s = b3[c];
    const float* wrow = w3 + (size_t)c*HID;
    for (int k=0;k<300;k++) s += wrow[k]*S2[r*304+k];
    out[(size_t)(r0+r)*7 + c] = s;
  }
}

// ---------------------------------------------------------------------------
extern "C" void kernel_launch(void* const* d_in, const int* in_sizes, int n_in,
                              void* d_out, int out_size, void* d_ws, size_t ws_size,
                              hipStream_t stream)
{
  (void)in_sizes; (void)n_in; (void)out_size; (void)ws_size;
  const float* feat  = (const float*)d_in[0];
  const int*   spk   = (const int*)d_in[1];
  const float* w_in  = (const float*)d_in[2];
  const float* b_in  = (const float*)d_in[3];
  const float* gwq   = (const float*)d_in[4];
  const float* gwk   = (const float*)d_in[5];
  const float* gb    = (const float*)d_in[6];
  const float* wr0   = (const float*)d_in[7];
  const float* wr1   = (const float*)d_in[8];
  const float* wih_c = (const float*)d_in[9];
  const float* whh_c = (const float*)d_in[10];
  const float* bih_c = (const float*)d_in[11];
  const float* bhh_c = (const float*)d_in[12];
  const float* wih_p = (const float*)d_in[13];
  const float* whh_p = (const float*)d_in[14];
  const float* bih_p = (const float*)d_in[15];
  const float* bhh_p = (const float*)d_in[16];
  const float* w1    = (const float*)d_in[17];
  const float* b1    = (const float*)d_in[18];
  const float* w2    = (const float*)d_in[19];
  const float* b2    = (const float*)d_in[20];
  const float* w3    = (const float*)d_in[21];
  const float* b3    = (const float*)d_in[22];
  float* out = (float*)d_out;

  char* ws = (char*)d_ws;
  size_t off = 0;
  auto alloc = [&](size_t bytes)->void*{
    void* p = ws + off;
    off += (bytes + 255) & ~(size_t)255;
    return p;
  };
  f16x2* W_M4 = (f16x2*)alloc((size_t)4*38*1800*4 * sizeof(f16x2));
  f16x2* WrT4 = (f16x2*)alloc((size_t)4*38*600*4  * sizeof(f16x2));
  f16x2* W_P4 = (f16x2*)alloc((size_t)4*38*1800*4 * sizeof(f16x2));
  f16x2* W_H4 = (f16x2*)alloc((size_t)128*300*4   * sizeof(f16x2));
  f16x2* W_14 = (f16x2*)alloc((size_t)318*304*4   * sizeof(f16x2));
  f16x2* W_24 = (f16x2*)alloc((size_t)38*304*4    * sizeof(f16x2));
  float* Hball = (float*)alloc((size_t)5*NROWS*HID*sizeof(float));
  float* xrow  = (float*)alloc((size_t)3*64*NSEQ*HID*sizeof(float));
  int*   syncc = (int*)alloc((size_t)(3*32*16 + 64)*sizeof(int));

  {
    const int tot = 4*38*1800*4 + 4*38*600*4 + 4*38*1800*4 + 128*300*4
                  + 318*304*4 + 38*304*4 + (3*32*16 + 64);
    convert_all_kernel<<<(tot+255)/256, 256, 0, stream>>>(whh_c, wih_p, wih_c, whh_p,
        wr0, wr1, w_in, w1, w2, W_M4, WrT4, W_P4, W_H4, W_14, W_24, syncc);
  }
  h0_kernel<<<NROWS/8, 256, 0, stream>>>(feat, W_H4, b_in, Hball);

  scan_pipe_kernel<<<128, 1024, 0, stream>>>(Hball, W_M4, WrT4, W_P4,
      bih_c, bhh_c, bih_p, bhh_p, gwq, gwk, gb, spk, xrow, syncc);

  head_kernel<<<NROWS/16, 256, 0, stream>>>(
      Hball, Hball + (size_t)NROWS*HID, Hball + (size_t)2*NROWS*HID,
      Hball + (size_t)3*NROWS*HID, Hball + (size_t)4*NROWS*HID,
      feat, W_14, b1, W_24, b2, w3, b3, out);
}

// Round 2
// 2366.532 us; speedup vs baseline: 1.1912x; 1.1912x over previous
//
#include <hip/hip_runtime.h>
#include <hip/hip_bf16.h>

typedef _Float16 f16x2 __attribute__((ext_vector_type(2)));

#define HID 300
#define NSEQ 64
#define NROWS 4096   // B*N = 64*64

union U { uint4 u; f16x2 h[4]; };

__device__ __forceinline__ float sigm(float x){ return 1.f/(1.f+__expf(-x)); }

__device__ __forceinline__ float fdot2a(f16x2 a, f16x2 b, float c){
#if __has_builtin(__builtin_amdgcn_fdot2)
  return __builtin_amdgcn_fdot2(a, b, c, false);
#else
  return c + (float)a.x*(float)b.x + (float)a.y*(float)b.y;
#endif
}

// Relaxed agent-scope ops: LLC-coherent, NO cache maintenance (no L2 flush).
__device__ __forceinline__ void xstore(float* p, float v){
  __hip_atomic_store(p, v, __ATOMIC_RELAXED, __HIP_MEMORY_SCOPE_AGENT);
}
__device__ __forceinline__ float xload(const float* p){
  return __hip_atomic_load(p, __ATOMIC_RELAXED, __HIP_MEMORY_SCOPE_AGENT);
}

// ---------------------------------------------------------------------------
// Merged repack: f32 -> fp16 pairs, [kg][outs][4 pairs] coalesced; also zeroes
// the pipeline sync counters + claim pools every launch.
// ---------------------------------------------------------------------------
__global__ void convert_all_kernel(
    const float* __restrict__ whh_c, const float* __restrict__ wih_p,
    const float* __restrict__ wih_c, const float* __restrict__ whh_p,
    const float* __restrict__ wr0,   const float* __restrict__ wr1,
    const float* __restrict__ w_in,  const float* __restrict__ w1,
    const float* __restrict__ w2,
    f16x2* __restrict__ W_M4, f16x2* __restrict__ WrT4, f16x2* __restrict__ W_P4,
    f16x2* __restrict__ W_H4, f16x2* __restrict__ W_14, f16x2* __restrict__ W_24,
    int* __restrict__ syncc)
{
  const int NA = 4*38*1800*4;
  const int NB = 4*38*600*4;
  const int NP = 4*38*1800*4;
  const int NH = 128*300*4;
  const int N1 = 318*304*4;
  const int N2 = 38*304*4;
  const int NS = 3*32*16 + 64;   // step counters (3 layers x 32 pairs) + claim pools
  const int TOT = NA+NB+NP+NH+N1+N2+NS;
  for (int idx0 = blockIdx.x*blockDim.x + threadIdx.x; idx0 < TOT; idx0 += gridDim.x*blockDim.x){
    int idx = idx0;
    if (idx < NA){
      int l    = idx/(38*1800*4);
      int rem  = idx - l*(38*1800*4);
      int kg   = rem/(1800*4);
      int rem2 = rem - kg*(1800*4);
      int o = rem2>>2, s = rem2&3;
      int c = (kg*4+s)*2;
      float v0=0.f, v1=0.f;
      if (c < 300){
        const float* src = (o<900) ? (whh_c + ((size_t)l*900+o)*300)
                                   : (wih_p + ((size_t)l*900+(o-900))*300);
        v0 = src[c]; v1 = src[c+1];
      }
      f16x2 t; t.x=(_Float16)v0; t.y=(_Float16)v1;
      W_M4[idx] = t; continue;
    }
    idx -= NA;
    if (idx < NB){
      int l    = idx/(38*600*4);
      int rem  = idx - l*(38*600*4);
      int kg   = rem/(600*4);
      int rem2 = rem - kg*(600*4);
      int t6 = rem2>>2, s = rem2&3;
      int d = t6>>1, hh = t6&1;
      int c = (kg*4+s)*2;
      float v0=0.f, v1=0.f;
      if (c < 300){
        const float* src = hh ? (wr1 + ((size_t)l*300+d)*300)
                              : (wr0 + ((size_t)l*300+d)*300);
        v0 = src[c]; v1 = src[c+1];
      }
      f16x2 t; t.x=(_Float16)v0; t.y=(_Float16)v1;
      WrT4[idx] = t; continue;
    }
    idx -= NB;
    if (idx < NP){
      int l    = idx/(38*1800*4);
      int rem  = idx - l*(38*1800*4);
      int kg   = rem/(1800*4);
      int rem2 = rem - kg*(1800*4);
      int o = rem2>>2, s = rem2&3;
      int c = (kg*4+s)*2;
      float v0=0.f, v1=0.f;
      if (c < 300){
        const float* src = (o<900) ? (wih_c + ((size_t)l*900+o)*300)
                                   : (whh_p + ((size_t)l*900+(o-900))*300);
        v0 = src[c]; v1 = src[c+1];
      }
      f16x2 t; t.x=(_Float16)v0; t.y=(_Float16)v1;
      W_P4[idx] = t; continue;
    }
    idx -= NP;
    if (idx < NH){
      int kg  = idx/(300*4);
      int rem = idx - kg*(300*4);
      int o = rem>>2, s = rem&3;
      int c = (kg*4+s)*2;
      f16x2 t; t.x=(_Float16)w_in[(size_t)o*1024+c]; t.y=(_Float16)w_in[(size_t)o*1024+c+1];
      W_H4[idx] = t; continue;
    }
    idx -= NH;
    if (idx < N1){
      int kgg = idx/(304*4);
      int rem = idx - kgg*(304*4);
      int o = rem>>2, s = rem&3;
      int segbase, seglen, kgl;
      if (kgg < 190){ int seg = kgg/38; kgl = kgg - seg*38; segbase = seg*300; seglen = 300; }
      else { int kk = kgg-190; int sf = kk>>6; kgl = kk&63; segbase = 1500 + sf*512; seglen = 512; }
      int c = (kgl*4+s)*2;
      float v0=0.f, v1=0.f;
      if (o < 300 && c < seglen){
        v0 = w1[(size_t)o*2524 + segbase + c];
        if (c+1 < seglen) v1 = w1[(size_t)o*2524 + segbase + c + 1];
      }
      f16x2 t; t.x=(_Float16)v0; t.y=(_Float16)v1;
      W_14[idx] = t; continue;
    }
    idx -= N1;
    if (idx < N2){
      int kg = idx/(304*4);
      int rem = idx - kg*(304*4);
      int o = rem>>2, s = rem&3;
      int c = (kg*4+s)*2;
      float v0=0.f, v1=0.f;
      if (o < 300 && c < 300){ v0 = w2[(size_t)o*300+c]; v1 = w2[(size_t)o*300+c+1]; }
      f16x2 t; t.x=(_Float16)v0; t.y=(_Float16)v1;
      W_24[idx] = t; continue;
    }
    idx -= N2;
    syncc[idx] = 0;
  }
}

// ---------------------------------------------------------------------------
// H0 = relu(features @ w_in^T + b_in), coalesced fp16 weights.
// ---------------------------------------------------------------------------
__global__ __launch_bounds__(256) void h0_kernel(const float* __restrict__ feat,
    const f16x2* __restrict__ WH, const float* __restrict__ b_in, float* __restrict__ H0)
{
  const int tid = threadIdx.x;
  const int r0  = blockIdx.x*8;
  __shared__ f16x2 X[8][512];
  for (int t=tid; t<8*512; t+=256){
    int r=t>>9, p=t&511, c=2*p;
    f16x2 h; h.x=(_Float16)feat[(size_t)(r0+r)*1024+c];
    h.y=(_Float16)feat[(size_t)(r0+r)*1024+c+1];
    X[r][p]=h;
  }
  __syncthreads();
  const uint4* WHu = (const uint4*)WH;
  const int o0 = tid, o1 = tid+256;
  const bool h1v = (o1 < 300);
  float acc[2][8];
  #pragma unroll
  for (int j=0;j<2;j++)
    #pragma unroll
    for (int r=0;r<8;r++) acc[j][r]=0.f;
  for (int kg=0; kg<128; kg++){
    U w0, w1;
    w0.u = WHu[(size_t)kg*300 + o0];
    if (h1v) w1.u = WHu[(size_t)kg*300 + o1];
    #pragma unroll
    for (int r=0;r<8;r++){
      const f16x2* xp = &X[r][kg*4];
      f16x2 x0=xp[0],x1=xp[1],x2=xp[2],x3=xp[3];
      acc[0][r] = fdot2a(w0.h[3],x3, fdot2a(w0.h[2],x2, fdot2a(w0.h[1],x1, fdot2a(w0.h[0],x0, acc[0][r]))));
      if (h1v)
        acc[1][r] = fdot2a(w1.h[3],x3, fdot2a(w1.h[2],x2, fdot2a(w1.h[1],x1, fdot2a(w1.h[0],x0, acc[1][r]))));
    }
  }
  {
    float bb = b_in[o0];
    #pragma unroll
    for (int r=0;r<8;r++) H0[(size_t)(r0+r)*HID + o0] = fmaxf(acc[0][r]+bb, 0.f);
  }
  if (h1v){
    float bb = b_in[o1];
    #pragma unroll
    for (int r=0;r<8;r++) H0[(size_t)(r0+r)*HID + o1] = fmaxf(acc[1][r]+bb, 0.f);
  }
}

// ---------------------------------------------------------------------------
// Fused 4-layer pipelined scan, 2 CHAINS PER WG: 128 WGs = 4 layers x 32 pairs.
// Round-0 codegen (plain kg loops, compiler scheduling) with two exact-math
// restructures kept from round 1:
//  - softmax is shift-invariant (q_i and gb cancel) -> A-phase computed in F
//    of the previous step from kd alone; the per-step q-dot in R is deleted.
//  - P phase therefore uses ALL 16 waves (1024 threads over 1800 outputs,
//    same o1/o2 mapping as the D phase).
// ---------------------------------------------------------------------------
__global__ __launch_bounds__(1024) void scan_pipe_kernel(
  float* __restrict__ Hball,
  const f16x2* __restrict__ W_M4, const f16x2* __restrict__ WrT4, const f16x2* __restrict__ W_P4,
  const float* __restrict__ bih_c, const float* __restrict__ bhh_c,
  const float* __restrict__ bih_p, const float* __restrict__ bhh_p,
  const float* __restrict__ gwq, const float* __restrict__ gwk, const float* __restrict__ gbv,
  const int* __restrict__ speakers, float* __restrict__ xrow, int* __restrict__ syncc)
{
  (void)gwq; (void)gbv;   // softmax is shift-invariant: q and b cancel exactly
  __shared__ _Float16 Hh[2][NSEQ][304];
  __shared__ float pre_s[2][1800];
  __shared__ float gates[2][1800];
  __shared__ float Mf[2][304];
  __shared__ f16x2 Mh[2][152];
  __shared__ f16x2 u01h[2][304];
  __shared__ float wgt[2][NSEQ];
  __shared__ float kd[2][NSEQ];
  __shared__ float red[2][320];
  __shared__ float xf[2][304];
  __shared__ f16x2 xh[2][152];
  __shared__ int   spk[2][NSEQ];
  __shared__ int   startA[2][NSEQ];
  __shared__ int   sLayer, sPair;

  const int tid = threadIdx.x;

  // --- claim (layer, pair) with XCD-local preference ---
  if (tid == 0){
    int xcc = 0;
    asm volatile("s_getreg_b32 %0, hwreg(HW_REG_XCC_ID)" : "=s"(xcc));
    int pref = (xcc >> 1) & 3;
    int* claimc = syncc + 3*32*16;
    int l = 0, p = 0;
    #pragma unroll 1
    for (int t=0; t<4; ++t){
      int cand = (pref + t) & 3;
      int idx = __hip_atomic_fetch_add(&claimc[cand*16], 1, __ATOMIC_RELAXED, __HIP_MEMORY_SCOPE_AGENT);
      if (idx < 32){ l = cand; p = idx; break; }
    }
    sLayer = l; sPair = p;
  }
  __syncthreads();
  const int layer = sLayer;
  const int pair  = sPair;
  const int base0 = (2*pair)*NSEQ;
  const int base1 = (2*pair+1)*NSEQ;

  const uint4* Wm4 = (const uint4*)(W_M4 + (size_t)layer*38*1800*4);
  const uint4* Wr4 = (const uint4*)(WrT4 + (size_t)layer*38*600*4);
  const uint4* Wp4 = (const uint4*)(W_P4 + (size_t)layer*38*1800*4);
  const float* HinB0 = Hball + (size_t)base0*300;
  const float* HinB1 = Hball + (size_t)base1*300;
  float* HoutB0 = Hball + ((size_t)(layer+1)*NROWS + (size_t)base0)*300;
  float* HoutB1 = Hball + ((size_t)(layer+1)*NROWS + (size_t)base1)*300;
  int* cntP = syncc + (layer*32 + pair)*16;
  int* cntC = (layer>0) ? (syncc + ((layer-1)*32 + pair)*16) : (int*)0;
  const float* xin  = xrow + (size_t)(((layer-1)*32 + pair)*2)*NSEQ*300;  // layer>0
  float*       xout = xrow + (size_t)((layer*32 + pair)*2)*NSEQ*300;      // layer<3

  const int w  = tid >> 6;     // wave id 0..15
  const int rc = tid >> 9;     // half 0/1 (chain for R/E phases)
  const int rt = tid & 511;

  // step-invariant per-thread regs (same for both halves)
  float bcr=0,bcz=0,bcn=0,bpr=0,bpz=0,bpn=0,wkv=0;
  if (rt < 300){
    bcr=bhh_c[layer*900+rt]; bcz=bhh_c[layer*900+300+rt]; bcn=bhh_c[layer*900+600+rt];
    bpr=bih_p[layer*900+rt]; bpz=bih_p[layer*900+300+rt]; bpn=bih_p[layer*900+600+rt];
    wkv=gwk[layer*300+rt];
  }

  // P/D output mapping: o1 = tid, o2 = tid+1024 (776 threads do 2 outputs)
  const int o1 = tid, o2 = tid+1024;
  const bool dhas2 = (o2 < 1800);
  float ppb1 = (o1<900) ? bih_c[layer*900+o1] : bhh_p[layer*900+o1-900];
  float ppb2 = 0.f;
  if (dhas2) ppb2 = (o2<900) ? bih_c[layer*900+o2] : bhh_p[layer*900+o2-900];

  // init
  if (tid < 64) spk[0][tid] = speakers[base0+tid];
  else if (tid < 128) spk[1][tid-64] = speakers[base1+(tid-64)];
  for (int t=tid; t<2*1800; t+=1024) ((float*)gates)[t]=0.f;
  for (int t=tid; t<2*304; t+=1024) ((float*)Mf)[t]=0.f;
  if (tid >= 128 && tid < 168){ int t=tid-128; red[t/20][300+(t%20)] = 0.f; }
  if (tid >= 168 && tid < 176){ int t=tid-168; xf[t>>2][300+(t&3)] = 0.f; }
  if (tid >= 176 && tid < 180){
    int t=tid-176; f16x2 z; z.x=(_Float16)0.f; z.y=(_Float16)0.f;
    Mh[t>>1][150+(t&1)]=z; xh[t>>1][150+(t&1)]=z;
    u01h[t>>1][150+(t&1)]=z; u01h[t>>1][302+(t&1)]=z;
  }
  __syncthreads();
  if (tid < 64){
    int s=0; for (int j=tid-1;j>=0;--j) if (spk[0][j]==spk[0][tid]){s=j;break;}
    startA[0][tid]=s;
  } else if (tid < 128){
    int t=tid-64;
    int s=0; for (int j=t-1;j>=0;--j) if (spk[1][j]==spk[1][t]){s=j;break;}
    startA[1][t]=s;
  }
  if (layer>0 && tid==0){
    while (__hip_atomic_load(cntC, __ATOMIC_RELAXED, __HIP_MEMORY_SCOPE_AGENT) < 1)
      __builtin_amdgcn_s_sleep(8);
  }
  __syncthreads();

  for (int i=0; i<NSEQ; ++i){
    // R: receive/load input row i for both chains
    if (rt < 150){
      float x0, x1;
      if (layer==0){
        const float* Hin = rc ? HinB1 : HinB0;
        float2 v = *(const float2*)(Hin + (size_t)i*300 + 2*rt);
        x0=v.x; x1=v.y;
      } else {
        const float* xi = xin + (size_t)rc*NSEQ*300 + (size_t)i*300;
        x0 = xload(xi + 2*rt);
        x1 = xload(xi + 2*rt + 1);
      }
      xf[rc][2*rt]=x0; xf[rc][2*rt+1]=x1;
      f16x2 h; h.x=(_Float16)x0; h.y=(_Float16)x1; xh[rc][rt]=h;
    }
    __syncthreads();
    // P: [wih_c ; whh_p] @ x, both chains per weight load, all 16 waves
    {
      float aA0=0,aA1=0,aA2=0,aA3=0, aB0=0,aB1=0,aB2=0,aB3=0;
      float eA0=0,eA1=0,eA2=0,eA3=0, eB0=0,eB1=0,eB2=0,eB3=0;
      for (int kg=0;kg<38;kg++){
        U v0, v1;
        v0.u = Wp4[(size_t)kg*1800 + o1];
        if (dhas2) v1.u = Wp4[(size_t)kg*1800 + o2];
        f16x2 xA0=xh[0][kg*4+0],xA1=xh[0][kg*4+1],xA2=xh[0][kg*4+2],xA3=xh[0][kg*4+3];
        f16x2 xB0=xh[1][kg*4+0],xB1=xh[1][kg*4+1],xB2=xh[1][kg*4+2],xB3=xh[1][kg*4+3];
        aA0=fdot2a(v0.h[0],xA0,aA0); aA1=fdot2a(v0.h[1],xA1,aA1);
        aA2=fdot2a(v0.h[2],xA2,aA2); aA3=fdot2a(v0.h[3],xA3,aA3);
        aB0=fdot2a(v0.h[0],xB0,aB0); aB1=fdot2a(v0.h[1],xB1,aB1);
        aB2=fdot2a(v0.h[2],xB2,aB2); aB3=fdot2a(v0.h[3],xB3,aB3);
        if (dhas2){
          eA0=fdot2a(v1.h[0],xA0,eA0); eA1=fdot2a(v1.h[1],xA1,eA1);
          eA2=fdot2a(v1.h[2],xA2,eA2); eA3=fdot2a(v1.h[3],xA3,eA3);
          eB0=fdot2a(v1.h[0],xB0,eB0); eB1=fdot2a(v1.h[1],xB1,eB1);
          eB2=fdot2a(v1.h[2],xB2,eB2); eB3=fdot2a(v1.h[3],xB3,eB3);
        }
      }
      pre_s[0][o1] = (aA0+aA1)+(aA2+aA3) + ppb1;
      pre_s[1][o1] = (aB0+aB1)+(aB2+aB3) + ppb1;
      if (dhas2){
        pre_s[0][o2] = (eA0+eA1)+(eA2+eA3) + ppb2;
        pre_s[1][o2] = (eB0+eB1)+(eB2+eB3) + ppb2;
      }
    }
    __syncthreads();
    if (i > 0){
      // B: weighted history sums, 1200 tasks (600 x 2 chains) over 1024 threads
      #pragma unroll 1
      for (int pass=0; pass<2; ++pass){
        int T = tid + pass*1024;
        if (T < 1200){
          const int c = (T >= 600);
          const int t = T - c*600;
          const int d  = (t<300)? t : (t-300);
          const int wh = (t>=300);
          const int st = startA[c][i]; const int ms = spk[c][i];
          float u=0.f;
          for (int j=st;j<i;++j){
            float sel = ((spk[c][j]==ms) != (wh!=0)) ? 1.f : 0.f;
            u += sel*wgt[c][j]*(float)Hh[c][j][d];
          }
          ((_Float16*)&u01h[c][0])[(wh?304:0) + d] = (_Float16)u;
        }
      }
      __syncthreads();
      // C: M = wr0@u0 + wr1@u1, both chains per weight load
      if (tid < 600){
        const int hh = tid&1;
        const f16x2* uA = (const f16x2*)&u01h[0][0] + hh*152;
        const f16x2* uB = (const f16x2*)&u01h[1][0] + hh*152;
        float a0=0,a1=0,a2=0,a3=0, b0=0,b1=0,b2=0,b3=0;
        for (int kg=0;kg<38;kg++){
          U v; v.u = Wr4[(size_t)kg*600 + tid];
          a0=fdot2a(v.h[0],uA[kg*4+0],a0); a1=fdot2a(v.h[1],uA[kg*4+1],a1);
          a2=fdot2a(v.h[2],uA[kg*4+2],a2); a3=fdot2a(v.h[3],uA[kg*4+3],a3);
          b0=fdot2a(v.h[0],uB[kg*4+0],b0); b1=fdot2a(v.h[1],uB[kg*4+1],b1);
          b2=fdot2a(v.h[2],uB[kg*4+2],b2); b3=fdot2a(v.h[3],uB[kg*4+3],b3);
        }
        float aA = (a0+a1)+(a2+a3);
        float aB = (b0+b1)+(b2+b3);
        float m2A = aA + __shfl_xor(aA,1);
        float m2B = aB + __shfl_xor(aB,1);
        if ((tid&1)==0){ Mf[0][tid>>1] = m2A; Mf[1][tid>>1] = m2B; }
        float moA = __shfl_xor(m2A,2);
        float moB = __shfl_xor(m2B,2);
        if ((tid&3)==0){
          f16x2 hA; hA.x=(_Float16)m2A; hA.y=(_Float16)moA; Mh[0][tid>>2]=hA;
          f16x2 hB; hB.x=(_Float16)m2B; hB.y=(_Float16)moB; Mh[1][tid>>2]=hB;
        }
      }
      __syncthreads();
      // D: gates = [whh_c ; wih_p] @ M, both chains per weight load
      {
        float aA0=0,aA1=0,aA2=0,aA3=0, aB0=0,aB1=0,aB2=0,aB3=0;
        float eA0=0,eA1=0,eA2=0,eA3=0, eB0=0,eB1=0,eB2=0,eB3=0;
        for (int kg=0;kg<38;kg++){
          U v0, v1;
          v0.u = Wm4[(size_t)kg*1800 + o1];
          if (dhas2) v1.u = Wm4[(size_t)kg*1800 + o2];
          f16x2 mA0=Mh[0][kg*4+0], mA1=Mh[0][kg*4+1], mA2=Mh[0][kg*4+2], mA3=Mh[0][kg*4+3];
          f16x2 mB0=Mh[1][kg*4+0], mB1=Mh[1][kg*4+1], mB2=Mh[1][kg*4+2], mB3=Mh[1][kg*4+3];
          aA0=fdot2a(v0.h[0],mA0,aA0); aA1=fdot2a(v0.h[1],mA1,aA1);
          aA2=fdot2a(v0.h[2],mA2,aA2); aA3=fdot2a(v0.h[3],mA3,aA3);
          aB0=fdot2a(v0.h[0],mB0,aB0); aB1=fdot2a(v0.h[1],mB1,aB1);
          aB2=fdot2a(v0.h[2],mB2,aB2); aB3=fdot2a(v0.h[3],mB3,aB3);
          if (dhas2){
            eA0=fdot2a(v1.h[0],mA0,eA0); eA1=fdot2a(v1.h[1],mA1,eA1);
            eA2=fdot2a(v1.h[2],mA2,eA2); eA3=fdot2a(v1.h[3],mA3,eA3);
            eB0=fdot2a(v1.h[0],mB0,eB0); eB1=fdot2a(v1.h[1],mB1,eB1);
            eB2=fdot2a(v1.h[2],mB2,eB2); eB3=fdot2a(v1.h[3],mB3,eB3);
          }
        }
        gates[0][o1] = (aA0+aA1)+(aA2+aA3);
        gates[1][o1] = (aB0+aB1)+(aB2+aB3);
        if (dhas2){
          gates[0][o2] = (eA0+eA1)+(eA2+eA3);
          gates[1][o2] = (eB0+eB1)+(eB2+eB3);
        }
      }
      __syncthreads();
    }
    // E: GRU combine for chain rc on thread-halves
    if (rt < 300){
      const float M = Mf[rc][rt];
      const float* ps = pre_s[rc];
      const float* gs = gates[rc];
      float r  = sigm(ps[rt] + gs[rt] + bcr);
      float z  = sigm(ps[300+rt] + gs[300+rt] + bcz);
      float n  = tanhf(ps[600+rt] + r*(gs[600+rt]+bcn));
      float C  = (1.f-z)*n + z*M;
      float rp = sigm(gs[900+rt]+bpr + ps[900+rt]);
      float zp = sigm(gs[1200+rt]+bpz + ps[1200+rt]);
      float np = tanhf(gs[1500+rt]+bpn + rp*ps[1500+rt]);
      float qv = xf[rc][rt];
      float P  = (1.f-zp)*np + zp*qv;
      float h  = C + P;
      float* Ho = rc ? HoutB1 : HoutB0;
      Ho[(size_t)i*300 + rt] = h;
      Hh[rc][i][rt] = (_Float16)h;
      red[rc][rt] = h*wkv;
      if (layer<3) xstore(xout + (size_t)rc*NSEQ*300 + (size_t)i*300 + rt, h);
    }
    asm volatile("s_waitcnt vmcnt(0)" ::: "memory");   // drain publish before counting
    __syncthreads();
    // F: kd[c][i] reduce + A(i+1) softmax (q & b cancel) on waves 0,8;
    //    counter bump + poll on tid 0
    if (w==0 || w==8){
      const int c = (w==8);
      const int lane = tid & 63;
      float s = red[c][lane]+red[c][lane+64]+red[c][lane+128]+red[c][lane+192]+red[c][lane+256];
      #pragma unroll
      for (int o=32;o>0;o>>=1) s += __shfl_xor(s,o);
      if (lane==0) kd[c][i]=s;
      if (i+1 < NSEQ){
        const int st = startA[c][i+1];
        const bool in = (lane>=st) && (lane<=i);
        float kv = (lane==i) ? s : kd[c][lane];
        float a = in ? kv : -3.0e38f;
        float m = a;
        #pragma unroll
        for (int o=32;o>0;o>>=1) m = fmaxf(m,__shfl_xor(m,o));
        float e = in ? __expf(a-m) : 0.f;
        float ss = e;
        #pragma unroll
        for (int o=32;o>0;o>>=1) ss += __shfl_xor(ss,o);
        wgt[c][lane] = e/ss;
      }
    }
    if (tid==0){
      if (layer<3) __hip_atomic_fetch_add(cntP, 1, __ATOMIC_RELAXED, __HIP_MEMORY_SCOPE_AGENT);
      if (layer>0 && i<63){
        while (__hip_atomic_load(cntC, __ATOMIC_RELAXED, __HIP_MEMORY_SCOPE_AGENT) < i+2)
          __builtin_amdgcn_s_sleep(8);
      }
    }
    __syncthreads();
  }
}

// ---------------------------------------------------------------------------
// Head with fp16-dot2 GEMMs (unchanged).
// ---------------------------------------------------------------------------
__global__ __launch_bounds__(256) void head_kernel(
  const float* __restrict__ H0, const float* __restrict__ Hl1,
  const float* __restrict__ Hl2, const float* __restrict__ Hl3,
  const float* __restrict__ Hl4, const float* __restrict__ feat,
  const f16x2* __restrict__ W14, const float* __restrict__ b1,
  const f16x2* __restrict__ W24, const float* __restrict__ b2,
  const float* __restrict__ w3, const float* __restrict__ b3,
  float* __restrict__ out)
{
  const int tid = threadIdx.x;
  const int r0  = blockIdx.x*16;
  __shared__ f16x2 Xh[16*256];
  __shared__ _Float16 h1h[16*304];
  __shared__ float S2[16*304];
  const uint4* W14u = (const uint4*)W14;
  const uint4* W24u = (const uint4*)W24;

  float acc0[16], acc1[16];
  #pragma unroll
  for (int r=0;r<16;r++){ acc0[r]=0.f; acc1[r]=0.f; }
  const int o  = tid;
  const int o2 = tid + 256;
  const bool has2 = (o2 < 300);

  #pragma unroll
  for (int seg=0; seg<7; seg++){
    const float* src = (seg==0)?H0:(seg==1)?Hl1:(seg==2)?Hl2:(seg==3)?Hl3:(seg==4)?Hl4:feat;
    if (seg < 5){
      for (int t=tid; t<16*152; t+=256){
        int r=t/152, p=t-r*152, c=2*p;
        float v0 = (c<300)? src[(size_t)(r0+r)*300 + c] : 0.f;
        float v1 = (c+1<300)? src[(size_t)(r0+r)*300 + c+1] : 0.f;
        f16x2 h; h.x=(_Float16)v0; h.y=(_Float16)v1;
        Xh[r*256+p] = h;
      }
    } else {
      const int cb = (seg-5)*512;
      for (int t=tid; t<16*256; t+=256){
        int r=t>>8, p=t&255;
        float v0 = src[(size_t)(r0+r)*1024 + cb + 2*p];
        float v1 = src[(size_t)(r0+r)*1024 + cb + 2*p+1];
        f16x2 h; h.x=(_Float16)v0; h.y=(_Float16)v1;
        Xh[r*256+p] = h;
      }
    }
    __syncthreads();
    const int kgs = (seg<5)?38:64;
    const int kgo = (seg<5)? seg*38 : 190+(seg-5)*64;
    if (o < 300){
      for (int kg=0; kg<kgs; kg++){
        U a, b;
        a.u = W14u[(size_t)(kgo+kg)*304 + o];
        if (has2) b.u = W14u[(size_t)(kgo+kg)*304 + o2];
        #pragma unroll
        for (int r=0;r<16;r++){
          const f16x2* xp = &Xh[r*256 + kg*4];
          float t0 = fdot2a(a.h[0], xp[0], 0.f);
          t0 = fdot2a(a.h[1], xp[1], t0);
          t0 = fdot2a(a.h[2], xp[2], t0);
          t0 = fdot2a(a.h[3], xp[3], t0);
          acc0[r] += t0;
          if (has2){
            float t1 = fdot2a(b.h[0], xp[0], 0.f);
            t1 = fdot2a(b.h[1], xp[1], t1);
            t1 = fdot2a(b.h[2], xp[2], t1);
            t1 = fdot2a(b.h[3], xp[3], t1);
            acc1[r] += t1;
          }
        }
      }
    }
    __syncthreads();
  }
  if (o < 300){
    float bb = b1[o];
    #pragma unroll
    for (int r=0;r<16;r++) h1h[r*304+o] = (_Float16)fmaxf(acc0[r]+bb, 0.f);
  }
  if (has2){
    float bb = b1[o2];
    #pragma unroll
    for (int r=0;r<16;r++) h1h[r*304+o2] = (_Float16)fmaxf(acc1[r]+bb, 0.f);
  }
  if (tid < 4){
    #pragma unroll
    for (int r=0;r<16;r++) h1h[r*304+300+tid] = (_Float16)0.f;
  }
  __syncthreads();
  #pragma unroll
  for (int r=0;r<16;r++){ acc0[r]=0.f; acc1[r]=0.f; }
  if (o < 300){
    for (int kg=0; kg<38; kg++){
      U a, b;
      a.u = W24u[(size_t)kg*304 + o];
      if (has2) b.u = W24u[(size_t)kg*304 + o2];
      #pragma unroll
      for (int r=0;r<16;r++){
        const f16x2* xp = (const f16x2*)&h1h[r*304] + kg*4;
        float t0 = fdot2a(a.h[0], xp[0], 0.f);
        t0 = fdot2a(a.h[1], xp[1], t0);
        t0 = fdot2a(a.h[2], xp[2], t0);
        t0 = fdot2a(a.h[3], xp[3], t0);
        acc0[r] += t0;
        if (has2){
          float t1 = fdot2a(b.h[0], xp[0], 0.f);
          t1 = fdot2a(b.h[1], xp[1], t1);
          t1 = fdot2a(b.h[2], xp[2], t1);
          t1 = fdot2a(b.h[3], xp[3], t1);
          acc1[r] += t1;
        }
      }
    }
  }
  __syncthreads();
  if (o < 300){
    float bb = b2[o];
    #pragma unroll
    for (int r=0;r<16;r++) S2[r*304+o] = fmaxf(acc0[r]+bb, 0.f);
  }
  if (has2){
    float bb = b2[o2];
    #pragma unroll
    for (int r=0;r<16;r++) S2[r*304+o2] = fmaxf(acc1[r]+bb, 0.f);
  }
  __syncthreads();
  if (tid < 16*7){
    int r = tid/7, c = tid - r*7;
    float s = b3[c];
    const float* wrow = w3 + (size_t)c*HID;
    for (int k=0;k<300;k++) s += wrow[k]*S2[r*304+k];
    out[(size_t)(r0+r)*7 + c] = s;
  }
}

// ---------------------------------------------------------------------------
extern "C" void kernel_launch(void* const* d_in, const int* in_sizes, int n_in,
                              void* d_out, int out_size, void* d_ws, size_t ws_size,
                              hipStream_t stream)
{
  (void)in_sizes; (void)n_in; (void)out_size; (void)ws_size;
  const float* feat  = (const float*)d_in[0];
  const int*   spk   = (const int*)d_in[1];
  const float* w_in  = (const float*)d_in[2];
  const float* b_in  = (const float*)d_in[3];
  const float* gwq   = (const float*)d_in[4];
  const float* gwk   = (const float*)d_in[5];
  const float* gb    = (const float*)d_in[6];
  const float* wr0   = (const float*)d_in[7];
  const float* wr1   = (const float*)d_in[8];
  const float* wih_c = (const float*)d_in[9];
  const float* whh_c = (const float*)d_in[10];
  const float* bih_c = (const float*)d_in[11];
  const float* bhh_c = (const float*)d_in[12];
  const float* wih_p = (const float*)d_in[13];
  const float* whh_p = (const float*)d_in[14];
  const float* bih_p = (const float*)d_in[15];
  const float* bhh_p = (const float*)d_in[16];
  const float* w1    = (const float*)d_in[17];
  const float* b1    = (const float*)d_in[18];
  const float* w2    = (const float*)d_in[19];
  const float* b2    = (const float*)d_in[20];
  const float* w3    = (const float*)d_in[21];
  const float* b3    = (const float*)d_in[22];
  float* out = (float*)d_out;

  char* ws = (char*)d_ws;
  size_t off = 0;
  auto alloc = [&](size_t bytes)->void*{
    void* p = ws + off;
    off += (bytes + 255) & ~(size_t)255;
    return p;
  };
  f16x2* W_M4 = (f16x2*)alloc((size_t)4*38*1800*4 * sizeof(f16x2));
  f16x2* WrT4 = (f16x2*)alloc((size_t)4*38*600*4  * sizeof(f16x2));
  f16x2* W_P4 = (f16x2*)alloc((size_t)4*38*1800*4 * sizeof(f16x2));
  f16x2* W_H4 = (f16x2*)alloc((size_t)128*300*4   * sizeof(f16x2));
  f16x2* W_14 = (f16x2*)alloc((size_t)318*304*4   * sizeof(f16x2));
  f16x2* W_24 = (f16x2*)alloc((size_t)38*304*4    * sizeof(f16x2));
  float* Hball = (float*)alloc((size_t)5*NROWS*HID*sizeof(float));
  float* xrow  = (float*)alloc((size_t)3*64*NSEQ*HID*sizeof(float));
  int*   syncc = (int*)alloc((size_t)(3*32*16 + 64)*sizeof(int));

  {
    const int tot = 4*38*1800*4 + 4*38*600*4 + 4*38*1800*4 + 128*300*4
                  + 318*304*4 + 38*304*4 + (3*32*16 + 64);
    convert_all_kernel<<<(tot+255)/256, 256, 0, stream>>>(whh_c, wih_p, wih_c, whh_p,
        wr0, wr1, w_in, w1, w2, W_M4, WrT4, W_P4, W_H4, W_14, W_24, syncc);
  }
  h0_kernel<<<NROWS/8, 256, 0, stream>>>(feat, W_H4, b_in, Hball);

  scan_pipe_kernel<<<128, 1024, 0, stream>>>(Hball, W_M4, WrT4, W_P4,
      bih_c, bhh_c, bih_p, bhh_p, gwq, gwk, gb, spk, xrow, syncc);

  head_kernel<<<NROWS/16, 256, 0, stream>>>(
      Hball, Hball + (size_t)NROWS*HID, Hball + (size_t)2*NROWS*HID,
      Hball + (size_t)3*NROWS*HID, Hball + (size_t)4*NROWS*HID,
      feat, W_14, b1, W_24, b2, w3, b3, out);
}

// Round 3
// 2046.337 us; speedup vs baseline: 1.3775x; 1.1565x over previous
//
#include <hip/hip_runtime.h>
#include <hip/hip_bf16.h>

typedef _Float16 f16x2 __attribute__((ext_vector_type(2)));

#define HID 300
#define NSEQ 64
#define NROWS 4096   // B*N = 64*64

union U { uint4 u; f16x2 h[4]; };

__device__ __forceinline__ float sigm(float x){ return 1.f/(1.f+__expf(-x)); }

__device__ __forceinline__ float fdot2a(f16x2 a, f16x2 b, float c){
#if __has_builtin(__builtin_amdgcn_fdot2)
  return __builtin_amdgcn_fdot2(a, b, c, false);
#else
  return c + (float)a.x*(float)b.x + (float)a.y*(float)b.y;
#endif
}

// Relaxed agent-scope ops: LLC-coherent, NO cache maintenance (no L2 flush).
__device__ __forceinline__ void xstore(float* p, float v){
  __hip_atomic_store(p, v, __ATOMIC_RELAXED, __HIP_MEMORY_SCOPE_AGENT);
}
__device__ __forceinline__ float xload(const float* p){
  return __hip_atomic_load(p, __ATOMIC_RELAXED, __HIP_MEMORY_SCOPE_AGENT);
}
__device__ __forceinline__ int xloadi(const int* p){
  return __hip_atomic_load(p, __ATOMIC_RELAXED, __HIP_MEMORY_SCOPE_AGENT);
}

// sync area layout (ints):
//   [0, 1536)            : cross-layer step counters (3 layers x 32 pairs x 16)
//   [1536, 1536+4096)    : fP flags   (128 pairs x 2 halves x 16)
//   [5632, 5632+4096)    : fC flags
//   [9728, 9728+4096)    : fD flags
//   [13824, 13824+64)    : claim pools (4 layers x 16)
#define NSYNC (3*32*16 + 3*128*2*16 + 64)

// ---------------------------------------------------------------------------
// Merged repack: f32 -> fp16 pairs, [kg][outs][4 pairs] coalesced; also zeroes
// the pipeline sync counters + claim pools every launch.
// ---------------------------------------------------------------------------
__global__ void convert_all_kernel(
    const float* __restrict__ whh_c, const float* __restrict__ wih_p,
    const float* __restrict__ wih_c, const float* __restrict__ whh_p,
    const float* __restrict__ wr0,   const float* __restrict__ wr1,
    const float* __restrict__ w_in,  const float* __restrict__ w1,
    const float* __restrict__ w2,
    f16x2* __restrict__ W_M4, f16x2* __restrict__ WrT4, f16x2* __restrict__ W_P4,
    f16x2* __restrict__ W_H4, f16x2* __restrict__ W_14, f16x2* __restrict__ W_24,
    int* __restrict__ syncc)
{
  const int NA = 4*38*1800*4;
  const int NB = 4*38*600*4;
  const int NP = 4*38*1800*4;
  const int NH = 128*300*4;
  const int N1 = 318*304*4;
  const int N2 = 38*304*4;
  const int NS = NSYNC;
  const int TOT = NA+NB+NP+NH+N1+N2+NS;
  for (int idx0 = blockIdx.x*blockDim.x + threadIdx.x; idx0 < TOT; idx0 += gridDim.x*blockDim.x){
    int idx = idx0;
    if (idx < NA){
      int l    = idx/(38*1800*4);
      int rem  = idx - l*(38*1800*4);
      int kg   = rem/(1800*4);
      int rem2 = rem - kg*(1800*4);
      int o = rem2>>2, s = rem2&3;
      int c = (kg*4+s)*2;
      float v0=0.f, v1=0.f;
      if (c < 300){
        const float* src = (o<900) ? (whh_c + ((size_t)l*900+o)*300)
                                   : (wih_p + ((size_t)l*900+(o-900))*300);
        v0 = src[c]; v1 = src[c+1];
      }
      f16x2 t; t.x=(_Float16)v0; t.y=(_Float16)v1;
      W_M4[idx] = t; continue;
    }
    idx -= NA;
    if (idx < NB){
      int l    = idx/(38*600*4);
      int rem  = idx - l*(38*600*4);
      int kg   = rem/(600*4);
      int rem2 = rem - kg*(600*4);
      int t6 = rem2>>2, s = rem2&3;
      int d = t6>>1, hh = t6&1;
      int c = (kg*4+s)*2;
      float v0=0.f, v1=0.f;
      if (c < 300){
        const float* src = hh ? (wr1 + ((size_t)l*300+d)*300)
                              : (wr0 + ((size_t)l*300+d)*300);
        v0 = src[c]; v1 = src[c+1];
      }
      f16x2 t; t.x=(_Float16)v0; t.y=(_Float16)v1;
      WrT4[idx] = t; continue;
    }
    idx -= NB;
    if (idx < NP){
      int l    = idx/(38*1800*4);
      int rem  = idx - l*(38*1800*4);
      int kg   = rem/(1800*4);
      int rem2 = rem - kg*(1800*4);
      int o = rem2>>2, s = rem2&3;
      int c = (kg*4+s)*2;
      float v0=0.f, v1=0.f;
      if (c < 300){
        const float* src = (o<900) ? (wih_c + ((size_t)l*900+o)*300)
                                   : (whh_p + ((size_t)l*900+(o-900))*300);
        v0 = src[c]; v1 = src[c+1];
      }
      f16x2 t; t.x=(_Float16)v0; t.y=(_Float16)v1;
      W_P4[idx] = t; continue;
    }
    idx -= NP;
    if (idx < NH){
      int kg  = idx/(300*4);
      int rem = idx - kg*(300*4);
      int o = rem>>2, s = rem&3;
      int c = (kg*4+s)*2;
      f16x2 t; t.x=(_Float16)w_in[(size_t)o*1024+c]; t.y=(_Float16)w_in[(size_t)o*1024+c+1];
      W_H4[idx] = t; continue;
    }
    idx -= NH;
    if (idx < N1){
      int kgg = idx/(304*4);
      int rem = idx - kgg*(304*4);
      int o = rem>>2, s = rem&3;
      int segbase, seglen, kgl;
      if (kgg < 190){ int seg = kgg/38; kgl = kgg - seg*38; segbase = seg*300; seglen = 300; }
      else { int kk = kgg-190; int sf = kk>>6; kgl = kk&63; segbase = 1500 + sf*512; seglen = 512; }
      int c = (kgl*4+s)*2;
      float v0=0.f, v1=0.f;
      if (o < 300 && c < seglen){
        v0 = w1[(size_t)o*2524 + segbase + c];
        if (c+1 < seglen) v1 = w1[(size_t)o*2524 + segbase + c + 1];
      }
      f16x2 t; t.x=(_Float16)v0; t.y=(_Float16)v1;
      W_14[idx] = t; continue;
    }
    idx -= N1;
    if (idx < N2){
      int kg = idx/(304*4);
      int rem = idx - kg*(304*4);
      int o = rem>>2, s = rem&3;
      int c = (kg*4+s)*2;
      float v0=0.f, v1=0.f;
      if (o < 300 && c < 300){ v0 = w2[(size_t)o*300+c]; v1 = w2[(size_t)o*300+c+1]; }
      f16x2 t; t.x=(_Float16)v0; t.y=(_Float16)v1;
      W_24[idx] = t; continue;
    }
    idx -= N2;
    syncc[idx] = 0;
  }
}

// ---------------------------------------------------------------------------
// H0 = relu(features @ w_in^T + b_in), coalesced fp16 weights.
// ---------------------------------------------------------------------------
__global__ __launch_bounds__(256) void h0_kernel(const float* __restrict__ feat,
    const f16x2* __restrict__ WH, const float* __restrict__ b_in, float* __restrict__ H0)
{
  const int tid = threadIdx.x;
  const int r0  = blockIdx.x*8;
  __shared__ f16x2 X[8][512];
  for (int t=tid; t<8*512; t+=256){
    int r=t>>9, p=t&511, c=2*p;
    f16x2 h; h.x=(_Float16)feat[(size_t)(r0+r)*1024+c];
    h.y=(_Float16)feat[(size_t)(r0+r)*1024+c+1];
    X[r][p]=h;
  }
  __syncthreads();
  const uint4* WHu = (const uint4*)WH;
  const int o0 = tid, o1 = tid+256;
  const bool h1v = (o1 < 300);
  float acc[2][8];
  #pragma unroll
  for (int j=0;j<2;j++)
    #pragma unroll
    for (int r=0;r<8;r++) acc[j][r]=0.f;
  for (int kg=0; kg<128; kg++){
    U w0, w1;
    w0.u = WHu[(size_t)kg*300 + o0];
    if (h1v) w1.u = WHu[(size_t)kg*300 + o1];
    #pragma unroll
    for (int r=0;r<8;r++){
      const f16x2* xp = &X[r][kg*4];
      f16x2 x0=xp[0],x1=xp[1],x2=xp[2],x3=xp[3];
      acc[0][r] = fdot2a(w0.h[3],x3, fdot2a(w0.h[2],x2, fdot2a(w0.h[1],x1, fdot2a(w0.h[0],x0, acc[0][r]))));
      if (h1v)
        acc[1][r] = fdot2a(w1.h[3],x3, fdot2a(w1.h[2],x2, fdot2a(w1.h[1],x1, fdot2a(w1.h[0],x0, acc[1][r]))));
    }
  }
  {
    float bb = b_in[o0];
    #pragma unroll
    for (int r=0;r<8;r++) H0[(size_t)(r0+r)*HID + o0] = fmaxf(acc[0][r]+bb, 0.f);
  }
  if (h1v){
    float bb = b_in[o1];
    #pragma unroll
    for (int r=0;r<8;r++) H0[(size_t)(r0+r)*HID + o1] = fmaxf(acc[1][r]+bb, 0.f);
  }
}

// ---------------------------------------------------------------------------
// Fused 4-layer pipelined scan, SPLIT ACROSS PAIRED WGs: 256 WGs =
// 4 layers x 32 pairs x 2 halves. Each half streams HALF the weight bytes
// (P/D rows [900h,900h+900), C rows [300h,300h+300)) -> per-CU weight
// traffic 2.55 MB -> 1.28 MB per step, using all 256 CUs. Partner halves
// exchanged via LLC (agent-scope): pre_s (step-parity ping-pong), Mf, gates.
// B/E/F are VALU-cheap and run redundantly in both halves.
// ---------------------------------------------------------------------------
__global__ __launch_bounds__(1024) void scan_pipe_kernel(
  float* __restrict__ Hball,
  const f16x2* __restrict__ W_M4, const f16x2* __restrict__ WrT4, const f16x2* __restrict__ W_P4,
  const float* __restrict__ bih_c, const float* __restrict__ bhh_c,
  const float* __restrict__ bih_p, const float* __restrict__ bhh_p,
  const float* __restrict__ gwq, const float* __restrict__ gwk, const float* __restrict__ gbv,
  const int* __restrict__ speakers, float* __restrict__ xrow, int* __restrict__ syncc,
  float* __restrict__ xpre, float* __restrict__ xgat, float* __restrict__ xm)
{
  (void)gwq; (void)gbv;   // softmax is shift-invariant: q and b cancel exactly
  __shared__ _Float16 Hh[2][NSEQ][304];
  __shared__ float pre_s[2][1800];
  __shared__ float gates[2][1800];
  __shared__ float Mf[2][304];
  __shared__ f16x2 Mh[2][152];
  __shared__ f16x2 u01h[2][304];
  __shared__ float wgt[2][NSEQ];
  __shared__ float kd[2][NSEQ];
  __shared__ float red[2][320];
  __shared__ float xf[2][304];
  __shared__ f16x2 xh[2][152];
  __shared__ int   spk[2][NSEQ];
  __shared__ int   startA[2][NSEQ];
  __shared__ int   sLayer, sPair, sHalf;

  const int tid = threadIdx.x;

  // --- claim (layer, pair, half) with XCD-local preference; 64 slots/layer ---
  if (tid == 0){
    int xcc = 0;
    asm volatile("s_getreg_b32 %0, hwreg(HW_REG_XCC_ID)" : "=s"(xcc));
    int pref = (xcc >> 1) & 3;
    int* claimc = syncc + 3*32*16 + 3*128*2*16;
    int l = 0, p = 0, hf = 0;
    #pragma unroll 1
    for (int t=0; t<4; ++t){
      int cand = (pref + t) & 3;
      int idx = __hip_atomic_fetch_add(&claimc[cand*16], 1, __ATOMIC_RELAXED, __HIP_MEMORY_SCOPE_AGENT);
      if (idx < 64){ l = cand; p = idx>>1; hf = idx&1; break; }
    }
    sLayer = l; sPair = p; sHalf = hf;
  }
  __syncthreads();
  const int layer = sLayer;
  const int pair  = sPair;
  const int hf    = sHalf;
  const int base0 = (2*pair)*NSEQ;
  const int base1 = (2*pair+1)*NSEQ;

  const uint4* Wm4 = (const uint4*)(W_M4 + (size_t)layer*38*1800*4);
  const uint4* Wr4 = (const uint4*)(WrT4 + (size_t)layer*38*600*4);
  const uint4* Wp4 = (const uint4*)(W_P4 + (size_t)layer*38*1800*4);
  const float* HinB0 = Hball + (size_t)base0*300;
  const float* HinB1 = Hball + (size_t)base1*300;
  float* HoutB0 = Hball + ((size_t)(layer+1)*NROWS + (size_t)base0)*300;
  float* HoutB1 = Hball + ((size_t)(layer+1)*NROWS + (size_t)base1)*300;
  int* cntP = syncc + (layer*32 + pair)*16;
  int* cntC = (layer>0) ? (syncc + ((layer-1)*32 + pair)*16) : (int*)0;
  const float* xin  = xrow + (size_t)(((layer-1)*32 + pair)*2)*NSEQ*300;  // layer>0
  float*       xout = xrow + (size_t)((layer*32 + pair)*2)*NSEQ*300;      // layer<3

  // exchange pointers
  const int lp = layer*32 + pair;
  float* xpreMy = xpre + ((size_t)lp*2 + hf)*3600;      // 2 parities x [c][900]
  const float* xprePt = xpre + ((size_t)lp*2 + (1-hf))*3600;
  float* xgatMy = xgat + ((size_t)lp*2 + hf)*1800;      // [c][900]
  const float* xgatPt = xgat + ((size_t)lp*2 + (1-hf))*1800;
  float* xmMy = xm + ((size_t)lp*2 + hf)*320;           // [c][160]
  const float* xmPt = xm + ((size_t)lp*2 + (1-hf))*320;
  int* fPmy = syncc + 1536 + (lp*2 + hf)*16;
  const int* fPpt = syncc + 1536 + (lp*2 + (1-hf))*16;
  int* fCmy = syncc + 1536 + 4096 + (lp*2 + hf)*16;
  const int* fCpt = syncc + 1536 + 4096 + (lp*2 + (1-hf))*16;
  int* fDmy = syncc + 1536 + 8192 + (lp*2 + hf)*16;
  const int* fDpt = syncc + 1536 + 8192 + (lp*2 + (1-hf))*16;

  const int w  = tid >> 6;     // wave id 0..15
  const int rc = tid >> 9;     // half 0/1 (chain for R/E phases)
  const int rt = tid & 511;

  // step-invariant per-thread regs (same for both halves)
  float bcr=0,bcz=0,bcn=0,bpr=0,bpz=0,bpn=0,wkv=0;
  if (rt < 300){
    bcr=bhh_c[layer*900+rt]; bcz=bhh_c[layer*900+300+rt]; bcn=bhh_c[layer*900+600+rt];
    bpr=bih_p[layer*900+rt]; bpz=bih_p[layer*900+300+rt]; bpn=bih_p[layer*900+600+rt];
    wkv=gwk[layer*300+rt];
  }

  // P/D output: this half covers [hf*900, hf*900+900), one output per tid<900
  float ppb = 0.f;
  if (tid < 900){
    const int op = hf*900 + tid;
    ppb = (op<900) ? bih_c[layer*900+op] : bhh_p[layer*900+(op-900)];
  }

  // init
  if (tid < 64) spk[0][tid] = speakers[base0+tid];
  else if (tid < 128) spk[1][tid-64] = speakers[base1+(tid-64)];
  for (int t=tid; t<2*1800; t+=1024) ((float*)gates)[t]=0.f;
  for (int t=tid; t<2*304; t+=1024) ((float*)Mf)[t]=0.f;
  if (tid >= 128 && tid < 168){ int t=tid-128; red[t/20][300+(t%20)] = 0.f; }
  if (tid >= 168 && tid < 176){ int t=tid-168; xf[t>>2][300+(t&3)] = 0.f; }
  if (tid >= 176 && tid < 180){
    int t=tid-176; f16x2 z; z.x=(_Float16)0.f; z.y=(_Float16)0.f;
    Mh[t>>1][150+(t&1)]=z; xh[t>>1][150+(t&1)]=z;
    u01h[t>>1][150+(t&1)]=z; u01h[t>>1][302+(t&1)]=z;
  }
  __syncthreads();
  if (tid < 64){
    int s=0; for (int j=tid-1;j>=0;--j) if (spk[0][j]==spk[0][tid]){s=j;break;}
    startA[0][tid]=s;
  } else if (tid < 128){
    int t=tid-64;
    int s=0; for (int j=t-1;j>=0;--j) if (spk[1][j]==spk[1][t]){s=j;break;}
    startA[1][t]=s;
  }
  if (layer>0 && tid==0){
    while (xloadi(cntC) < 1) __builtin_amdgcn_s_sleep(8);
  }
  __syncthreads();

  for (int i=0; i<NSEQ; ++i){
    // R: receive/load input row i for both chains
    if (rt < 150){
      float x0, x1;
      if (layer==0){
        const float* Hin = rc ? HinB1 : HinB0;
        float2 v = *(const float2*)(Hin + (size_t)i*300 + 2*rt);
        x0=v.x; x1=v.y;
      } else {
        const float* xi = xin + (size_t)rc*NSEQ*300 + (size_t)i*300;
        x0 = xload(xi + 2*rt);
        x1 = xload(xi + 2*rt + 1);
      }
      xf[rc][2*rt]=x0; xf[rc][2*rt+1]=x1;
      f16x2 h; h.x=(_Float16)x0; h.y=(_Float16)x1; xh[rc][rt]=h;
    }
    __syncthreads();
    // P: [wih_c ; whh_p] @ x — this half's 900 rows, both chains per load
    if (tid < 900){
      const int op = hf*900 + tid;
      float aA0=0,aA1=0,aA2=0,aA3=0, aB0=0,aB1=0,aB2=0,aB3=0;
      for (int kg=0;kg<38;kg++){
        U v; v.u = Wp4[(size_t)kg*1800 + op];
        f16x2 xA0=xh[0][kg*4+0],xA1=xh[0][kg*4+1],xA2=xh[0][kg*4+2],xA3=xh[0][kg*4+3];
        f16x2 xB0=xh[1][kg*4+0],xB1=xh[1][kg*4+1],xB2=xh[1][kg*4+2],xB3=xh[1][kg*4+3];
        aA0=fdot2a(v.h[0],xA0,aA0); aA1=fdot2a(v.h[1],xA1,aA1);
        aA2=fdot2a(v.h[2],xA2,aA2); aA3=fdot2a(v.h[3],xA3,aA3);
        aB0=fdot2a(v.h[0],xB0,aB0); aB1=fdot2a(v.h[1],xB1,aB1);
        aB2=fdot2a(v.h[2],xB2,aB2); aB3=fdot2a(v.h[3],xB3,aB3);
      }
      float rA = (aA0+aA1)+(aA2+aA3) + ppb;
      float rB = (aB0+aB1)+(aB2+aB3) + ppb;
      pre_s[0][op] = rA; pre_s[1][op] = rB;
      float* xp = xpreMy + (i&1)*1800;
      xstore(xp + tid, rA);
      xstore(xp + 900 + tid, rB);
    }
    asm volatile("s_waitcnt vmcnt(0)" ::: "memory");
    __syncthreads();
    if (tid==0) __hip_atomic_fetch_add(fPmy, 1, __ATOMIC_RELAXED, __HIP_MEMORY_SCOPE_AGENT);

    if (i == 0){
      // import partner pre_s half (parity 0)
      if (tid==0){
        while (xloadi(fPpt) < 1) __builtin_amdgcn_s_sleep(1);
      }
      __syncthreads();
      if (tid < 900){
        const int hp = 1-hf;
        pre_s[0][hp*900+tid] = xload(xprePt + tid);
        pre_s[1][hp*900+tid] = xload(xprePt + 900 + tid);
      }
      __syncthreads();
    } else {
      // B: weighted history sums, 1200 tasks, redundant in both halves
      #pragma unroll 1
      for (int pass=0; pass<2; ++pass){
        int T = tid + pass*1024;
        if (T < 1200){
          const int c = (T >= 600);
          const int t = T - c*600;
          const int d  = (t<300)? t : (t-300);
          const int wh = (t>=300);
          const int st = startA[c][i]; const int ms = spk[c][i];
          float u=0.f;
          for (int j=st;j<i;++j){
            float sel = ((spk[c][j]==ms) != (wh!=0)) ? 1.f : 0.f;
            u += sel*wgt[c][j]*(float)Hh[c][j][d];
          }
          ((_Float16*)&u01h[c][0])[(wh?304:0) + d] = (_Float16)u;
        }
      }
      __syncthreads();
      // C: M = wr0@u0 + wr1@u1 — this half's 300 of 600 rows
      if (tid < 300){
        const int idx600 = hf*300 + tid;
        const int hh = idx600&1;
        const f16x2* uA = (const f16x2*)&u01h[0][0] + hh*152;
        const f16x2* uB = (const f16x2*)&u01h[1][0] + hh*152;
        float a0=0,a1=0,a2=0,a3=0, b0=0,b1=0,b2=0,b3=0;
        for (int kg=0;kg<38;kg++){
          U v; v.u = Wr4[(size_t)kg*600 + idx600];
          a0=fdot2a(v.h[0],uA[kg*4+0],a0); a1=fdot2a(v.h[1],uA[kg*4+1],a1);
          a2=fdot2a(v.h[2],uA[kg*4+2],a2); a3=fdot2a(v.h[3],uA[kg*4+3],a3);
          b0=fdot2a(v.h[0],uB[kg*4+0],b0); b1=fdot2a(v.h[1],uB[kg*4+1],b1);
          b2=fdot2a(v.h[2],uB[kg*4+2],b2); b3=fdot2a(v.h[3],uB[kg*4+3],b3);
        }
        float aA = (a0+a1)+(a2+a3);
        float aB = (b0+b1)+(b2+b3);
        float m2A = aA + __shfl_xor(aA,1);
        float m2B = aB + __shfl_xor(aB,1);
        float moA = __shfl_xor(m2A,2);
        float moB = __shfl_xor(m2B,2);
        if ((tid&1)==0){
          const int d = idx600>>1;
          Mf[0][d] = m2A; Mf[1][d] = m2B;
          xstore(xmMy + (tid>>1), m2A);
          xstore(xmMy + 160 + (tid>>1), m2B);
        }
        if ((tid&3)==0){
          f16x2 hA; hA.x=(_Float16)m2A; hA.y=(_Float16)moA; Mh[0][idx600>>2]=hA;
          f16x2 hB; hB.x=(_Float16)m2B; hB.y=(_Float16)moB; Mh[1][idx600>>2]=hB;
        }
      }
      asm volatile("s_waitcnt vmcnt(0)" ::: "memory");
      __syncthreads();
      if (tid==0){
        __hip_atomic_fetch_add(fCmy, 1, __ATOMIC_RELAXED, __HIP_MEMORY_SCOPE_AGENT);
        while (xloadi(fCpt) < i) __builtin_amdgcn_s_sleep(1);
      }
      __syncthreads();
      // import partner Mf/Mh (150 d-values)
      if (tid < 75){
        const int hp = 1-hf;
        float a0 = xload(xmPt + 2*tid);
        float a1 = xload(xmPt + 2*tid + 1);
        float b0 = xload(xmPt + 160 + 2*tid);
        float b1 = xload(xmPt + 160 + 2*tid + 1);
        const int d0 = hp*150 + 2*tid;
        Mf[0][d0] = a0; Mf[0][d0+1] = a1;
        Mf[1][d0] = b0; Mf[1][d0+1] = b1;
        f16x2 hA; hA.x=(_Float16)a0; hA.y=(_Float16)a1;
        f16x2 hB; hB.x=(_Float16)b0; hB.y=(_Float16)b1;
        Mh[0][hp*75+tid] = hA;
        Mh[1][hp*75+tid] = hB;
      }
      __syncthreads();
      // D: gates = [whh_c ; wih_p] @ M — this half's 900 rows
      if (tid < 900){
        const int op = hf*900 + tid;
        float aA0=0,aA1=0,aA2=0,aA3=0, aB0=0,aB1=0,aB2=0,aB3=0;
        for (int kg=0;kg<38;kg++){
          U v; v.u = Wm4[(size_t)kg*1800 + op];
          f16x2 mA0=Mh[0][kg*4+0], mA1=Mh[0][kg*4+1], mA2=Mh[0][kg*4+2], mA3=Mh[0][kg*4+3];
          f16x2 mB0=Mh[1][kg*4+0], mB1=Mh[1][kg*4+1], mB2=Mh[1][kg*4+2], mB3=Mh[1][kg*4+3];
          aA0=fdot2a(v.h[0],mA0,aA0); aA1=fdot2a(v.h[1],mA1,aA1);
          aA2=fdot2a(v.h[2],mA2,aA2); aA3=fdot2a(v.h[3],mA3,aA3);
          aB0=fdot2a(v.h[0],mB0,aB0); aB1=fdot2a(v.h[1],mB1,aB1);
          aB2=fdot2a(v.h[2],mB2,aB2); aB3=fdot2a(v.h[3],mB3,aB3);
        }
        float gA = (aA0+aA1)+(aA2+aA3);
        float gB = (aB0+aB1)+(aB2+aB3);
        gates[0][op] = gA; gates[1][op] = gB;
        xstore(xgatMy + tid, gA);
        xstore(xgatMy + 900 + tid, gB);
      }
      asm volatile("s_waitcnt vmcnt(0)" ::: "memory");
      __syncthreads();
      if (tid==0){
        __hip_atomic_fetch_add(fDmy, 1, __ATOMIC_RELAXED, __HIP_MEMORY_SCOPE_AGENT);
        while (xloadi(fDpt) < i) __builtin_amdgcn_s_sleep(1);
      }
      __syncthreads();
      // import partner pre_s (parity i&1) + gates halves
      if (tid < 900){
        const int hp = 1-hf;
        const float* xp = xprePt + (i&1)*1800;
        pre_s[0][hp*900+tid] = xload(xp + tid);
        pre_s[1][hp*900+tid] = xload(xp + 900 + tid);
        gates[0][hp*900+tid] = xload(xgatPt + tid);
        gates[1][hp*900+tid] = xload(xgatPt + 900 + tid);
      }
      __syncthreads();
    }
    // E: GRU combine for chain rc on thread-halves (redundant in both halves)
    if (rt < 300){
      const float M = Mf[rc][rt];
      const float* ps = pre_s[rc];
      const float* gs = gates[rc];
      float r  = sigm(ps[rt] + gs[rt] + bcr);
      float z  = sigm(ps[300+rt] + gs[300+rt] + bcz);
      float n  = tanhf(ps[600+rt] + r*(gs[600+rt]+bcn));
      float C  = (1.f-z)*n + z*M;
      float rp = sigm(gs[900+rt]+bpr + ps[900+rt]);
      float zp = sigm(gs[1200+rt]+bpz + ps[1200+rt]);
      float np = tanhf(gs[1500+rt]+bpn + rp*ps[1500+rt]);
      float qv = xf[rc][rt];
      float P  = (1.f-zp)*np + zp*qv;
      float h  = C + P;
      Hh[rc][i][rt] = (_Float16)h;
      red[rc][rt] = h*wkv;
      if (hf==0){
        float* Ho = rc ? HoutB1 : HoutB0;
        Ho[(size_t)i*300 + rt] = h;
        if (layer<3) xstore(xout + (size_t)rc*NSEQ*300 + (size_t)i*300 + rt, h);
      }
    }
    asm volatile("s_waitcnt vmcnt(0)" ::: "memory");   // drain publish before counting
    __syncthreads();
    // F: kd[c][i] reduce + A(i+1) softmax (q & b cancel) on waves 0,8;
    //    counter bump (half 0) + cross-layer poll on tid 0
    if (w==0 || w==8){
      const int c = (w==8);
      const int lane = tid & 63;
      float s = red[c][lane]+red[c][lane+64]+red[c][lane+128]+red[c][lane+192]+red[c][lane+256];
      #pragma unroll
      for (int o=32;o>0;o>>=1) s += __shfl_xor(s,o);
      if (lane==0) kd[c][i]=s;
      if (i+1 < NSEQ){
        const int st = startA[c][i+1];
        const bool in = (lane>=st) && (lane<=i);
        float kv = (lane==i) ? s : kd[c][lane];
        float a = in ? kv : -3.0e38f;
        float m = a;
        #pragma unroll
        for (int o=32;o>0;o>>=1) m = fmaxf(m,__shfl_xor(m,o));
        float e = in ? __expf(a-m) : 0.f;
        float ss = e;
        #pragma unroll
        for (int o=32;o>0;o>>=1) ss += __shfl_xor(ss,o);
        wgt[c][lane] = e/ss;
      }
    }
    if (tid==0){
      if (layer<3 && hf==0) __hip_atomic_fetch_add(cntP, 1, __ATOMIC_RELAXED, __HIP_MEMORY_SCOPE_AGENT);
      if (layer>0 && i<63){
        while (xloadi(cntC) < i+2) __builtin_amdgcn_s_sleep(8);
      }
    }
    __syncthreads();
  }
}

// ---------------------------------------------------------------------------
// Head with fp16-dot2 GEMMs (unchanged).
// ---------------------------------------------------------------------------
__global__ __launch_bounds__(256) void head_kernel(
  const float* __restrict__ H0, const float* __restrict__ Hl1,
  const float* __restrict__ Hl2, const float* __restrict__ Hl3,
  const float* __restrict__ Hl4, const float* __restrict__ feat,
  const f16x2* __restrict__ W14, const float* __restrict__ b1,
  const f16x2* __restrict__ W24, const float* __restrict__ b2,
  const float* __restrict__ w3, const float* __restrict__ b3,
  float* __restrict__ out)
{
  const int tid = threadIdx.x;
  const int r0  = blockIdx.x*16;
  __shared__ f16x2 Xh[16*256];
  __shared__ _Float16 h1h[16*304];
  __shared__ float S2[16*304];
  const uint4* W14u = (const uint4*)W14;
  const uint4* W24u = (const uint4*)W24;

  float acc0[16], acc1[16];
  #pragma unroll
  for (int r=0;r<16;r++){ acc0[r]=0.f; acc1[r]=0.f; }
  const int o  = tid;
  const int o2 = tid + 256;
  const bool has2 = (o2 < 300);

  #pragma unroll
  for (int seg=0; seg<7; seg++){
    const float* src = (seg==0)?H0:(seg==1)?Hl1:(seg==2)?Hl2:(seg==3)?Hl3:(seg==4)?Hl4:feat;
    if (seg < 5){
      for (int t=tid; t<16*152; t+=256){
        int r=t/152, p=t-r*152, c=2*p;
        float v0 = (c<300)? src[(size_t)(r0+r)*300 + c] : 0.f;
        float v1 = (c+1<300)? src[(size_t)(r0+r)*300 + c+1] : 0.f;
        f16x2 h; h.x=(_Float16)v0; h.y=(_Float16)v1;
        Xh[r*256+p] = h;
      }
    } else {
      const int cb = (seg-5)*512;
      for (int t=tid; t<16*256; t+=256){
        int r=t>>8, p=t&255;
        float v0 = src[(size_t)(r0+r)*1024 + cb + 2*p];
        float v1 = src[(size_t)(r0+r)*1024 + cb + 2*p+1];
        f16x2 h; h.x=(_Float16)v0; h.y=(_Float16)v1;
        Xh[r*256+p] = h;
      }
    }
    __syncthreads();
    const int kgs = (seg<5)?38:64;
    const int kgo = (seg<5)? seg*38 : 190+(seg-5)*64;
    if (o < 300){
      for (int kg=0; kg<kgs; kg++){
        U a, b;
        a.u = W14u[(size_t)(kgo+kg)*304 + o];
        if (has2) b.u = W14u[(size_t)(kgo+kg)*304 + o2];
        #pragma unroll
        for (int r=0;r<16;r++){
          const f16x2* xp = &Xh[r*256 + kg*4];
          float t0 = fdot2a(a.h[0], xp[0], 0.f);
          t0 = fdot2a(a.h[1], xp[1], t0);
          t0 = fdot2a(a.h[2], xp[2], t0);
          t0 = fdot2a(a.h[3], xp[3], t0);
          acc0[r] += t0;
          if (has2){
            float t1 = fdot2a(b.h[0], xp[0], 0.f);
            t1 = fdot2a(b.h[1], xp[1], t1);
            t1 = fdot2a(b.h[2], xp[2], t1);
            t1 = fdot2a(b.h[3], xp[3], t1);
            acc1[r] += t1;
          }
        }
      }
    }
    __syncthreads();
  }
  if (o < 300){
    float bb = b1[o];
    #pragma unroll
    for (int r=0;r<16;r++) h1h[r*304+o] = (_Float16)fmaxf(acc0[r]+bb, 0.f);
  }
  if (has2){
    float bb = b1[o2];
    #pragma unroll
    for (int r=0;r<16;r++) h1h[r*304+o2] = (_Float16)fmaxf(acc1[r]+bb, 0.f);
  }
  if (tid < 4){
    #pragma unroll
    for (int r=0;r<16;r++) h1h[r*304+300+tid] = (_Float16)0.f;
  }
  __syncthreads();
  #pragma unroll
  for (int r=0;r<16;r++){ acc0[r]=0.f; acc1[r]=0.f; }
  if (o < 300){
    for (int kg=0; kg<38; kg++){
      U a, b;
      a.u = W24u[(size_t)kg*304 + o];
      if (has2) b.u = W24u[(size_t)kg*304 + o2];
      #pragma unroll
      for (int r=0;r<16;r++){
        const f16x2* xp = (const f16x2*)&h1h[r*304] + kg*4;
        float t0 = fdot2a(a.h[0], xp[0], 0.f);
        t0 = fdot2a(a.h[1], xp[1], t0);
        t0 = fdot2a(a.h[2], xp[2], t0);
        t0 = fdot2a(a.h[3], xp[3], t0);
        acc0[r] += t0;
        if (has2){
          float t1 = fdot2a(b.h[0], xp[0], 0.f);
          t1 = fdot2a(b.h[1], xp[1], t1);
          t1 = fdot2a(b.h[2], xp[2], t1);
          t1 = fdot2a(b.h[3], xp[3], t1);
          acc1[r] += t1;
        }
      }
    }
  }
  __syncthreads();
  if (o < 300){
    float bb = b2[o];
    #pragma unroll
    for (int r=0;r<16;r++) S2[r*304+o] = fmaxf(acc0[r]+bb, 0.f);
  }
  if (has2){
    float bb = b2[o2];
    #pragma unroll
    for (int r=0;r<16;r++) S2[r*304+o2] = fmaxf(acc1[r]+bb, 0.f);
  }
  __syncthreads();
  if (tid < 16*7){
    int r = tid/7, c = tid - r*7;
    float s = b3[c];
    const float* wrow = w3 + (size_t)c*HID;
    for (int k=0;k<300;k++) s += wrow[k]*S2[r*304+k];
    out[(size_t)(r0+r)*7 + c] = s;
  }
}

// ---------------------------------------------------------------------------
extern "C" void kernel_launch(void* const* d_in, const int* in_sizes, int n_in,
                              void* d_out, int out_size, void* d_ws, size_t ws_size,
                              hipStream_t stream)
{
  (void)in_sizes; (void)n_in; (void)out_size; (void)ws_size;
  const float* feat  = (const float*)d_in[0];
  const int*   spk   = (const int*)d_in[1];
  const float* w_in  = (const float*)d_in[2];
  const float* b_in  = (const float*)d_in[3];
  const float* gwq   = (const float*)d_in[4];
  const float* gwk   = (const float*)d_in[5];
  const float* gb    = (const float*)d_in[6];
  const float* wr0   = (const float*)d_in[7];
  const float* wr1   = (const float*)d_in[8];
  const float* wih_c = (const float*)d_in[9];
  const float* whh_c = (const float*)d_in[10];
  const float* bih_c = (const float*)d_in[11];
  const float* bhh_c = (const float*)d_in[12];
  const float* wih_p = (const float*)d_in[13];
  const float* whh_p = (const float*)d_in[14];
  const float* bih_p = (const float*)d_in[15];
  const float* bhh_p = (const float*)d_in[16];
  const float* w1    = (const float*)d_in[17];
  const float* b1    = (const float*)d_in[18];
  const float* w2    = (const float*)d_in[19];
  const float* b2    = (const float*)d_in[20];
  const float* w3    = (const float*)d_in[21];
  const float* b3    = (const float*)d_in[22];
  float* out = (float*)d_out;

  char* ws = (char*)d_ws;
  size_t off = 0;
  auto alloc = [&](size_t bytes)->void*{
    void* p = ws + off;
    off += (bytes + 255) & ~(size_t)255;
    return p;
  };
  f16x2* W_M4 = (f16x2*)alloc((size_t)4*38*1800*4 * sizeof(f16x2));
  f16x2* WrT4 = (f16x2*)alloc((size_t)4*38*600*4  * sizeof(f16x2));
  f16x2* W_P4 = (f16x2*)alloc((size_t)4*38*1800*4 * sizeof(f16x2));
  f16x2* W_H4 = (f16x2*)alloc((size_t)128*300*4   * sizeof(f16x2));
  f16x2* W_14 = (f16x2*)alloc((size_t)318*304*4   * sizeof(f16x2));
  f16x2* W_24 = (f16x2*)alloc((size_t)38*304*4    * sizeof(f16x2));
  float* Hball = (float*)alloc((size_t)5*NROWS*HID*sizeof(float));
  float* xrow  = (float*)alloc((size_t)3*64*NSEQ*HID*sizeof(float));
  int*   syncc = (int*)alloc((size_t)NSYNC*sizeof(int));
  float* xpre  = (float*)alloc((size_t)128*2*3600*sizeof(float));
  float* xgat  = (float*)alloc((size_t)128*2*1800*sizeof(float));
  float* xm    = (float*)alloc((size_t)128*2*320*sizeof(float));

  {
    const int tot = 4*38*1800*4 + 4*38*600*4 + 4*38*1800*4 + 128*300*4
                  + 318*304*4 + 38*304*4 + NSYNC;
    convert_all_kernel<<<(tot+255)/256, 256, 0, stream>>>(whh_c, wih_p, wih_c, whh_p,
        wr0, wr1, w_in, w1, w2, W_M4, WrT4, W_P4, W_H4, W_14, W_24, syncc);
  }
  h0_kernel<<<NROWS/8, 256, 0, stream>>>(feat, W_H4, b_in, Hball);

  scan_pipe_kernel<<<256, 1024, 0, stream>>>(Hball, W_M4, WrT4, W_P4,
      bih_c, bhh_c, bih_p, bhh_p, gwq, gwk, gb, spk, xrow, syncc,
      xpre, xgat, xm);

  head_kernel<<<NROWS/16, 256, 0, stream>>>(
      Hball, Hball + (size_t)NROWS*HID, Hball + (size_t)2*NROWS*HID,
      Hball + (size_t)3*NROWS*HID, Hball + (size_t)4*NROWS*HID,
      feat, W_14, b1, W_24, b2, w3, b3, out);
}

// Round 4
// 1791.826 us; speedup vs baseline: 1.5732x; 1.1420x over previous
//
#include <hip/hip_runtime.h>
#include <hip/hip_bf16.h>

typedef _Float16 f16x2 __attribute__((ext_vector_type(2)));

#define HID 300
#define NSEQ 64
#define NROWS 4096   // B*N = 64*64

union U { uint4 u; f16x2 h[4]; };

__device__ __forceinline__ float sigm(float x){ return 1.f/(1.f+__expf(-x)); }

__device__ __forceinline__ float fdot2a(f16x2 a, f16x2 b, float c){
#if __has_builtin(__builtin_amdgcn_fdot2)
  return __builtin_amdgcn_fdot2(a, b, c, false);
#else
  return c + (float)a.x*(float)b.x + (float)a.y*(float)b.y;
#endif
}

// Relaxed agent-scope ops: LLC-coherent, NO cache maintenance (no L2 flush).
__device__ __forceinline__ void xstore(float* p, float v){
  __hip_atomic_store(p, v, __ATOMIC_RELAXED, __HIP_MEMORY_SCOPE_AGENT);
}
__device__ __forceinline__ float xload(const float* p){
  return __hip_atomic_load(p, __ATOMIC_RELAXED, __HIP_MEMORY_SCOPE_AGENT);
}
__device__ __forceinline__ int xloadi(const int* p){
  return __hip_atomic_load(p, __ATOMIC_RELAXED, __HIP_MEMORY_SCOPE_AGENT);
}

// sync area layout (ints):
//   [0, 1536)            : cross-layer step counters (3 layers x 32 pairs x 16)
//   [1536, 1536+4096)    : fE flags (h-exchange, 128 pairs x 2 halves x 16)
//   [13824, 13824+64)    : claim pools (4 layers x 16)   (gap kept zeroed)
#define NSYNC (3*32*16 + 3*128*2*16 + 64)

// ---------------------------------------------------------------------------
// Merged repack: f32 -> fp16 pairs, [kg][outs][4 pairs] coalesced; also zeroes
// the pipeline sync counters + claim pools every launch.
// ---------------------------------------------------------------------------
__global__ void convert_all_kernel(
    const float* __restrict__ whh_c, const float* __restrict__ wih_p,
    const float* __restrict__ wih_c, const float* __restrict__ whh_p,
    const float* __restrict__ wr0,   const float* __restrict__ wr1,
    const float* __restrict__ w_in,  const float* __restrict__ w1,
    const float* __restrict__ w2,
    f16x2* __restrict__ W_M4, f16x2* __restrict__ WrT4, f16x2* __restrict__ W_P4,
    f16x2* __restrict__ W_H4, f16x2* __restrict__ W_14, f16x2* __restrict__ W_24,
    int* __restrict__ syncc)
{
  const int NA = 4*38*1800*4;
  const int NB = 4*38*600*4;
  const int NP = 4*38*1800*4;
  const int NH = 128*300*4;
  const int N1 = 318*304*4;
  const int N2 = 38*304*4;
  const int NS = NSYNC;
  const int TOT = NA+NB+NP+NH+N1+N2+NS;
  for (int idx0 = blockIdx.x*blockDim.x + threadIdx.x; idx0 < TOT; idx0 += gridDim.x*blockDim.x){
    int idx = idx0;
    if (idx < NA){
      int l    = idx/(38*1800*4);
      int rem  = idx - l*(38*1800*4);
      int kg   = rem/(1800*4);
      int rem2 = rem - kg*(1800*4);
      int o = rem2>>2, s = rem2&3;
      int c = (kg*4+s)*2;
      float v0=0.f, v1=0.f;
      if (c < 300){
        const float* src = (o<900) ? (whh_c + ((size_t)l*900+o)*300)
                                   : (wih_p + ((size_t)l*900+(o-900))*300);
        v0 = src[c]; v1 = src[c+1];
      }
      f16x2 t; t.x=(_Float16)v0; t.y=(_Float16)v1;
      W_M4[idx] = t; continue;
    }
    idx -= NA;
    if (idx < NB){
      int l    = idx/(38*600*4);
      int rem  = idx - l*(38*600*4);
      int kg   = rem/(600*4);
      int rem2 = rem - kg*(600*4);
      int t6 = rem2>>2, s = rem2&3;
      int d = t6>>1, hh = t6&1;
      int c = (kg*4+s)*2;
      float v0=0.f, v1=0.f;
      if (c < 300){
        const float* src = hh ? (wr1 + ((size_t)l*300+d)*300)
                              : (wr0 + ((size_t)l*300+d)*300);
        v0 = src[c]; v1 = src[c+1];
      }
      f16x2 t; t.x=(_Float16)v0; t.y=(_Float16)v1;
      WrT4[idx] = t; continue;
    }
    idx -= NB;
    if (idx < NP){
      int l    = idx/(38*1800*4);
      int rem  = idx - l*(38*1800*4);
      int kg   = rem/(1800*4);
      int rem2 = rem - kg*(1800*4);
      int o = rem2>>2, s = rem2&3;
      int c = (kg*4+s)*2;
      float v0=0.f, v1=0.f;
      if (c < 300){
        const float* src = (o<900) ? (wih_c + ((size_t)l*900+o)*300)
                                   : (whh_p + ((size_t)l*900+(o-900))*300);
        v0 = src[c]; v1 = src[c+1];
      }
      f16x2 t; t.x=(_Float16)v0; t.y=(_Float16)v1;
      W_P4[idx] = t; continue;
    }
    idx -= NP;
    if (idx < NH){
      int kg  = idx/(300*4);
      int rem = idx - kg*(300*4);
      int o = rem>>2, s = rem&3;
      int c = (kg*4+s)*2;
      f16x2 t; t.x=(_Float16)w_in[(size_t)o*1024+c]; t.y=(_Float16)w_in[(size_t)o*1024+c+1];
      W_H4[idx] = t; continue;
    }
    idx -= NH;
    if (idx < N1){
      int kgg = idx/(304*4);
      int rem = idx - kgg*(304*4);
      int o = rem>>2, s = rem&3;
      int segbase, seglen, kgl;
      if (kgg < 190){ int seg = kgg/38; kgl = kgg - seg*38; segbase = seg*300; seglen = 300; }
      else { int kk = kgg-190; int sf = kk>>6; kgl = kk&63; segbase = 1500 + sf*512; seglen = 512; }
      int c = (kgl*4+s)*2;
      float v0=0.f, v1=0.f;
      if (o < 300 && c < seglen){
        v0 = w1[(size_t)o*2524 + segbase + c];
        if (c+1 < seglen) v1 = w1[(size_t)o*2524 + segbase + c + 1];
      }
      f16x2 t; t.x=(_Float16)v0; t.y=(_Float16)v1;
      W_14[idx] = t; continue;
    }
    idx -= N1;
    if (idx < N2){
      int kg = idx/(304*4);
      int rem = idx - kg*(304*4);
      int o = rem>>2, s = rem&3;
      int c = (kg*4+s)*2;
      float v0=0.f, v1=0.f;
      if (o < 300 && c < 300){ v0 = w2[(size_t)o*300+c]; v1 = w2[(size_t)o*300+c+1]; }
      f16x2 t; t.x=(_Float16)v0; t.y=(_Float16)v1;
      W_24[idx] = t; continue;
    }
    idx -= N2;
    syncc[idx] = 0;
  }
}

// ---------------------------------------------------------------------------
// H0 = relu(features @ w_in^T + b_in), coalesced fp16 weights.
// ---------------------------------------------------------------------------
__global__ __launch_bounds__(256) void h0_kernel(const float* __restrict__ feat,
    const f16x2* __restrict__ WH, const float* __restrict__ b_in, float* __restrict__ H0)
{
  const int tid = threadIdx.x;
  const int r0  = blockIdx.x*8;
  __shared__ f16x2 X[8][512];
  for (int t=tid; t<8*512; t+=256){
    int r=t>>9, p=t&511, c=2*p;
    f16x2 h; h.x=(_Float16)feat[(size_t)(r0+r)*1024+c];
    h.y=(_Float16)feat[(size_t)(r0+r)*1024+c+1];
    X[r][p]=h;
  }
  __syncthreads();
  const uint4* WHu = (const uint4*)WH;
  const int o0 = tid, o1 = tid+256;
  const bool h1v = (o1 < 300);
  float acc[2][8];
  #pragma unroll
  for (int j=0;j<2;j++)
    #pragma unroll
    for (int r=0;r<8;r++) acc[j][r]=0.f;
  for (int kg=0; kg<128; kg++){
    U w0, w1;
    w0.u = WHu[(size_t)kg*300 + o0];
    if (h1v) w1.u = WHu[(size_t)kg*300 + o1];
    #pragma unroll
    for (int r=0;r<8;r++){
      const f16x2* xp = &X[r][kg*4];
      f16x2 x0=xp[0],x1=xp[1],x2=xp[2],x3=xp[3];
      acc[0][r] = fdot2a(w0.h[3],x3, fdot2a(w0.h[2],x2, fdot2a(w0.h[1],x1, fdot2a(w0.h[0],x0, acc[0][r]))));
      if (h1v)
        acc[1][r] = fdot2a(w1.h[3],x3, fdot2a(w1.h[2],x2, fdot2a(w1.h[1],x1, fdot2a(w1.h[0],x0, acc[1][r]))));
    }
  }
  {
    float bb = b_in[o0];
    #pragma unroll
    for (int r=0;r<8;r++) H0[(size_t)(r0+r)*HID + o0] = fmaxf(acc[0][r]+bb, 0.f);
  }
  if (h1v){
    float bb = b_in[o1];
    #pragma unroll
    for (int r=0;r<8;r++) H0[(size_t)(r0+r)*HID + o1] = fmaxf(acc[1][r]+bb, 0.f);
  }
}

// ---------------------------------------------------------------------------
// Fused 4-layer pipelined scan, d-SPLIT paired WGs: 256 WGs = 4 layers x
// 32 pairs x 2 halves. Half h owns gate-column range d in [150h,150h+150):
//   P,D stream rows {g*300+d} (half the weight bytes), E is fully LOCAL
//   (pre_s/gates/Mf never leave the WG). B full (needs full Hh), C full
//   redundant (needs full u; M then local). Only exchange: h itself,
//   300 f32/step, parity double-buffered, poll deferred to next step's
//   pre-B (hidden). kd+softmax (old F) also moved to pre-B.
// ---------------------------------------------------------------------------
__global__ __launch_bounds__(1024) void scan_pipe_kernel(
  float* __restrict__ Hball,
  const f16x2* __restrict__ W_M4, const f16x2* __restrict__ WrT4, const f16x2* __restrict__ W_P4,
  const float* __restrict__ bih_c, const float* __restrict__ bhh_c,
  const float* __restrict__ bih_p, const float* __restrict__ bhh_p,
  const float* __restrict__ gwq, const float* __restrict__ gwk, const float* __restrict__ gbv,
  const int* __restrict__ speakers, float* __restrict__ xrow, int* __restrict__ syncc,
  float* __restrict__ xhEx)
{
  (void)gwq; (void)gbv;   // softmax is shift-invariant: q and b cancel exactly
  __shared__ _Float16 Hh[2][NSEQ][304];
  __shared__ float pre_s[2][1800];
  __shared__ float gates[2][1800];
  __shared__ float Mf[2][304];
  __shared__ f16x2 Mh[2][152];
  __shared__ f16x2 u01h[2][304];
  __shared__ float wgt[2][NSEQ];
  __shared__ float kd[2][NSEQ];
  __shared__ float red[2][320];
  __shared__ float xf[2][304];
  __shared__ f16x2 xh[2][152];
  __shared__ int   spk[2][NSEQ];
  __shared__ int   startA[2][NSEQ];
  __shared__ int   sLayer, sPair, sHalf;

  const int tid = threadIdx.x;

  // --- claim (layer, pair, half) with XCD-local preference; 64 slots/layer ---
  if (tid == 0){
    int xcc = 0;
    asm volatile("s_getreg_b32 %0, hwreg(HW_REG_XCC_ID)" : "=s"(xcc));
    int pref = (xcc >> 1) & 3;
    int* claimc = syncc + 3*32*16 + 3*128*2*16;
    int l = 0, p = 0, hf = 0;
    #pragma unroll 1
    for (int t=0; t<4; ++t){
      int cand = (pref + t) & 3;
      int idx = __hip_atomic_fetch_add(&claimc[cand*16], 1, __ATOMIC_RELAXED, __HIP_MEMORY_SCOPE_AGENT);
      if (idx < 64){ l = cand; p = idx>>1; hf = idx&1; break; }
    }
    sLayer = l; sPair = p; sHalf = hf;
  }
  __syncthreads();
  const int layer = sLayer;
  const int pair  = sPair;
  const int hf    = sHalf;
  const int base0 = (2*pair)*NSEQ;
  const int base1 = (2*pair+1)*NSEQ;

  const uint4* Wm4 = (const uint4*)(W_M4 + (size_t)layer*38*1800*4);
  const uint4* Wr4 = (const uint4*)(WrT4 + (size_t)layer*38*600*4);
  const uint4* Wp4 = (const uint4*)(W_P4 + (size_t)layer*38*1800*4);
  const float* HinB0 = Hball + (size_t)base0*300;
  const float* HinB1 = Hball + (size_t)base1*300;
  float* HoutB0 = Hball + ((size_t)(layer+1)*NROWS + (size_t)base0)*300;
  float* HoutB1 = Hball + ((size_t)(layer+1)*NROWS + (size_t)base1)*300;
  int* cntP = syncc + (layer*32 + pair)*16;
  int* cntC = (layer>0) ? (syncc + ((layer-1)*32 + pair)*16) : (int*)0;
  const float* xin  = xrow + (size_t)(((layer-1)*32 + pair)*2)*NSEQ*300;  // layer>0
  float*       xout = xrow + (size_t)((layer*32 + pair)*2)*NSEQ*300;      // layer<3

  // h-exchange pointers: per half, 2 parity slots x (2 chains x 150) f32
  const int lp = layer*32 + pair;
  float* xhMy = xhEx + ((size_t)lp*2 + hf)*600;
  const float* xhPt = xhEx + ((size_t)lp*2 + (1-hf))*600;
  int* fEmy = syncc + 1536 + (lp*2 + hf)*16;
  const int* fEpt = syncc + 1536 + (lp*2 + (1-hf))*16;

  const int w  = tid >> 6;     // wave id 0..15
  const int rc = tid >> 9;     // half 0/1 (chain for R/E phases)
  const int rt = tid & 511;

  // E-phase per-thread regs (my d-range: d = hf*150 + rt, rt<150)
  float bcr=0,bcz=0,bcn=0,bpr=0,bpz=0,bpn=0,wkv=0;
  if (rt < 150){
    const int de = hf*150 + rt;
    bcr=bhh_c[layer*900+de]; bcz=bhh_c[layer*900+300+de]; bcn=bhh_c[layer*900+600+de];
    bpr=bih_p[layer*900+de]; bpz=bih_p[layer*900+300+de]; bpn=bih_p[layer*900+600+de];
    wkv=gwk[layer*300+de];
  }
  // import-phase per-thread reg (partner d-range)
  float wkp=0;
  if (tid < 300){
    const int r = (tid<150)? tid : (tid-150);
    wkp = gwk[layer*300 + (1-hf)*150 + r];
  }

  // P/D output mapping: tid<900 -> op = (tid/150)*300 + hf*150 + tid%150
  int opm = 0; float ppb = 0.f;
  if (tid < 900){
    const int g = tid/150;
    const int dd = tid - g*150;
    opm = g*300 + hf*150 + dd;
    ppb = (opm<900) ? bih_c[layer*900+opm] : bhh_p[layer*900+(opm-900)];
  }

  // init
  if (tid < 64) spk[0][tid] = speakers[base0+tid];
  else if (tid < 128) spk[1][tid-64] = speakers[base1+(tid-64)];
  for (int t=tid; t<2*1800; t+=1024) ((float*)gates)[t]=0.f;
  for (int t=tid; t<2*304; t+=1024) ((float*)Mf)[t]=0.f;
  if (tid >= 128 && tid < 168){ int t=tid-128; red[t/20][300+(t%20)] = 0.f; }
  if (tid >= 168 && tid < 176){ int t=tid-168; xf[t>>2][300+(t&3)] = 0.f; }
  if (tid >= 176 && tid < 180){
    int t=tid-176; f16x2 z; z.x=(_Float16)0.f; z.y=(_Float16)0.f;
    Mh[t>>1][150+(t&1)]=z; xh[t>>1][150+(t&1)]=z;
    u01h[t>>1][150+(t&1)]=z; u01h[t>>1][302+(t&1)]=z;
  }
  __syncthreads();
  if (tid < 64){
    int s=0; for (int j=tid-1;j>=0;--j) if (spk[0][j]==spk[0][tid]){s=j;break;}
    startA[0][tid]=s;
  } else if (tid < 128){
    int t=tid-64;
    int s=0; for (int j=t-1;j>=0;--j) if (spk[1][j]==spk[1][t]){s=j;break;}
    startA[1][t]=s;
  }
  if (layer>0 && tid==0){
    while (xloadi(cntC) < 2) __builtin_amdgcn_s_sleep(8);   // row 0: both halves
  }
  __syncthreads();

  for (int i=0; i<NSEQ; ++i){
    // R: receive/load input row i for both chains (full 300 per chain)
    if (rt < 150){
      float x0, x1;
      if (layer==0){
        const float* Hin = rc ? HinB1 : HinB0;
        float2 v = *(const float2*)(Hin + (size_t)i*300 + 2*rt);
        x0=v.x; x1=v.y;
      } else {
        const float* xi = xin + (size_t)rc*NSEQ*300 + (size_t)i*300;
        x0 = xload(xi + 2*rt);
        x1 = xload(xi + 2*rt + 1);
      }
      xf[rc][2*rt]=x0; xf[rc][2*rt+1]=x1;
      f16x2 h; h.x=(_Float16)x0; h.y=(_Float16)x1; xh[rc][rt]=h;
    }
    __syncthreads();
    // P: [wih_c ; whh_p] @ x — my 900 d-split rows, both chains per load
    if (tid < 900){
      float aA0=0,aA1=0,aA2=0,aA3=0, aB0=0,aB1=0,aB2=0,aB3=0;
      for (int kg=0;kg<38;kg++){
        U v; v.u = Wp4[(size_t)kg*1800 + opm];
        f16x2 xA0=xh[0][kg*4+0],xA1=xh[0][kg*4+1],xA2=xh[0][kg*4+2],xA3=xh[0][kg*4+3];
        f16x2 xB0=xh[1][kg*4+0],xB1=xh[1][kg*4+1],xB2=xh[1][kg*4+2],xB3=xh[1][kg*4+3];
        aA0=fdot2a(v.h[0],xA0,aA0); aA1=fdot2a(v.h[1],xA1,aA1);
        aA2=fdot2a(v.h[2],xA2,aA2); aA3=fdot2a(v.h[3],xA3,aA3);
        aB0=fdot2a(v.h[0],xB0,aB0); aB1=fdot2a(v.h[1],xB1,aB1);
        aB2=fdot2a(v.h[2],xB2,aB2); aB3=fdot2a(v.h[3],xB3,aB3);
      }
      pre_s[0][opm] = (aA0+aA1)+(aA2+aA3) + ppb;
      pre_s[1][opm] = (aB0+aB1)+(aB2+aB3) + ppb;
    }
    __syncthreads();
    if (i > 0){
      // PRE-B: import partner h(i-1) (flag published a full step ago -> warm),
      // complete red/Hh, then kd[i-1] + softmax -> wgt for this step's B.
      if (tid==0){
        while (xloadi(fEpt) < i) __builtin_amdgcn_s_sleep(1);
      }
      __syncthreads();
      if (tid < 300){
        const int c = (tid<150)? 0 : 1;
        const int r = tid - c*150;
        const int pd = (1-hf)*150 + r;
        float hv = xload(xhPt + ((i-1)&1)*300 + c*150 + r);
        red[c][pd] = hv * wkp;
        Hh[c][i-1][pd] = (_Float16)hv;
      }
      __syncthreads();
      if (w==0 || w==8){
        const int c = (w==8);
        const int lane = tid & 63;
        float s = red[c][lane]+red[c][lane+64]+red[c][lane+128]+red[c][lane+192]+red[c][lane+256];
        #pragma unroll
        for (int o=32;o>0;o>>=1) s += __shfl_xor(s,o);
        if (lane==0) kd[c][i-1]=s;
        {
          const int st = startA[c][i];
          const bool in = (lane>=st) && (lane<i);
          float kv = (lane==i-1) ? s : kd[c][lane];
          float a = in ? kv : -3.0e38f;
          float m = a;
          #pragma unroll
          for (int o=32;o>0;o>>=1) m = fmaxf(m,__shfl_xor(m,o));
          float e = in ? __expf(a-m) : 0.f;
          float ss = e;
          #pragma unroll
          for (int o=32;o>0;o>>=1) ss += __shfl_xor(ss,o);
          wgt[c][lane] = e/ss;
        }
      }
      __syncthreads();
      // B: weighted history sums, full 1200 tasks (needs full Hh)
      #pragma unroll 1
      for (int pass=0; pass<2; ++pass){
        int T = tid + pass*1024;
        if (T < 1200){
          const int c = (T >= 600);
          const int t = T - c*600;
          const int d  = (t<300)? t : (t-300);
          const int wh = (t>=300);
          const int st = startA[c][i]; const int ms = spk[c][i];
          float u=0.f;
          for (int j=st;j<i;++j){
            float sel = ((spk[c][j]==ms) != (wh!=0)) ? 1.f : 0.f;
            u += sel*wgt[c][j]*(float)Hh[c][j][d];
          }
          ((_Float16*)&u01h[c][0])[(wh?304:0) + d] = (_Float16)u;
        }
      }
      __syncthreads();
      // C: M = wr0@u0 + wr1@u1 — FULL redundant (M then local for D and E)
      if (tid < 600){
        const int hh = tid&1;
        const f16x2* uA = (const f16x2*)&u01h[0][0] + hh*152;
        const f16x2* uB = (const f16x2*)&u01h[1][0] + hh*152;
        float a0=0,a1=0,a2=0,a3=0, b0=0,b1=0,b2=0,b3=0;
        for (int kg=0;kg<38;kg++){
          U v; v.u = Wr4[(size_t)kg*600 + tid];
          a0=fdot2a(v.h[0],uA[kg*4+0],a0); a1=fdot2a(v.h[1],uA[kg*4+1],a1);
          a2=fdot2a(v.h[2],uA[kg*4+2],a2); a3=fdot2a(v.h[3],uA[kg*4+3],a3);
          b0=fdot2a(v.h[0],uB[kg*4+0],b0); b1=fdot2a(v.h[1],uB[kg*4+1],b1);
          b2=fdot2a(v.h[2],uB[kg*4+2],b2); b3=fdot2a(v.h[3],uB[kg*4+3],b3);
        }
        float aA = (a0+a1)+(a2+a3);
        float aB = (b0+b1)+(b2+b3);
        float m2A = aA + __shfl_xor(aA,1);
        float m2B = aB + __shfl_xor(aB,1);
        if ((tid&1)==0){ Mf[0][tid>>1] = m2A; Mf[1][tid>>1] = m2B; }
        float moA = __shfl_xor(m2A,2);
        float moB = __shfl_xor(m2B,2);
        if ((tid&3)==0){
          f16x2 hA; hA.x=(_Float16)m2A; hA.y=(_Float16)moA; Mh[0][tid>>2]=hA;
          f16x2 hB; hB.x=(_Float16)m2B; hB.y=(_Float16)moB; Mh[1][tid>>2]=hB;
        }
      }
      __syncthreads();
      // D: gates = [whh_c ; wih_p] @ M — my 900 d-split rows
      if (tid < 900){
        float aA0=0,aA1=0,aA2=0,aA3=0, aB0=0,aB1=0,aB2=0,aB3=0;
        for (int kg=0;kg<38;kg++){
          U v; v.u = Wm4[(size_t)kg*1800 + opm];
          f16x2 mA0=Mh[0][kg*4+0], mA1=Mh[0][kg*4+1], mA2=Mh[0][kg*4+2], mA3=Mh[0][kg*4+3];
          f16x2 mB0=Mh[1][kg*4+0], mB1=Mh[1][kg*4+1], mB2=Mh[1][kg*4+2], mB3=Mh[1][kg*4+3];
          aA0=fdot2a(v.h[0],mA0,aA0); aA1=fdot2a(v.h[1],mA1,aA1);
          aA2=fdot2a(v.h[2],mA2,aA2); aA3=fdot2a(v.h[3],mA3,aA3);
          aB0=fdot2a(v.h[0],mB0,aB0); aB1=fdot2a(v.h[1],mB1,aB1);
          aB2=fdot2a(v.h[2],mB2,aB2); aB3=fdot2a(v.h[3],mB3,aB3);
        }
        gates[0][opm] = (aA0+aA1)+(aA2+aA3);
        gates[1][opm] = (aB0+aB1)+(aB2+aB3);
      }
      __syncthreads();
    }
    // E: GRU combine for my d-range only (pre_s/gates/Mf all local)
    if (rt < 150){
      const int de = hf*150 + rt;
      const float M = Mf[rc][de];
      const float* ps = pre_s[rc];
      const float* gs = gates[rc];
      float r  = sigm(ps[de] + gs[de] + bcr);
      float z  = sigm(ps[300+de] + gs[300+de] + bcz);
      float n  = tanhf(ps[600+de] + r*(gs[600+de]+bcn));
      float C  = (1.f-z)*n + z*M;
      float rp = sigm(gs[900+de]+bpr + ps[900+de]);
      float zp = sigm(gs[1200+de]+bpz + ps[1200+de]);
      float np = tanhf(gs[1500+de]+bpn + rp*ps[1500+de]);
      float qv = xf[rc][de];
      float P  = (1.f-zp)*np + zp*qv;
      float h  = C + P;
      Hh[rc][i][de] = (_Float16)h;
      red[rc][de] = h*wkv;
      float* Ho = rc ? HoutB1 : HoutB0;
      Ho[(size_t)i*300 + de] = h;
      xstore(xhMy + (i&1)*300 + rc*150 + rt, h);
      if (layer<3) xstore(xout + (size_t)rc*NSEQ*300 + (size_t)i*300 + de, h);
    }
    asm volatile("s_waitcnt vmcnt(0)" ::: "memory");   // drain publish before flags
    __syncthreads();
    if (tid==0){
      __hip_atomic_fetch_add(fEmy, 1, __ATOMIC_RELAXED, __HIP_MEMORY_SCOPE_AGENT);
      if (layer<3) __hip_atomic_fetch_add(cntP, 1, __ATOMIC_RELAXED, __HIP_MEMORY_SCOPE_AGENT);
      if (layer>0 && i<63){
        while (xloadi(cntC) < 2*(i+2)) __builtin_amdgcn_s_sleep(8);
      }
    }
    __syncthreads();
  }
}

// ---------------------------------------------------------------------------
// Head with fp16-dot2 GEMMs (unchanged).
// ---------------------------------------------------------------------------
__global__ __launch_bounds__(256) void head_kernel(
  const float* __restrict__ H0, const float* __restrict__ Hl1,
  const float* __restrict__ Hl2, const float* __restrict__ Hl3,
  const float* __restrict__ Hl4, const float* __restrict__ feat,
  const f16x2* __restrict__ W14, const float* __restrict__ b1,
  const f16x2* __restrict__ W24, const float* __restrict__ b2,
  const float* __restrict__ w3, const float* __restrict__ b3,
  float* __restrict__ out)
{
  const int tid = threadIdx.x;
  const int r0  = blockIdx.x*16;
  __shared__ f16x2 Xh[16*256];
  __shared__ _Float16 h1h[16*304];
  __shared__ float S2[16*304];
  const uint4* W14u = (const uint4*)W14;
  const uint4* W24u = (const uint4*)W24;

  float acc0[16], acc1[16];
  #pragma unroll
  for (int r=0;r<16;r++){ acc0[r]=0.f; acc1[r]=0.f; }
  const int o  = tid;
  const int o2 = tid + 256;
  const bool has2 = (o2 < 300);

  #pragma unroll
  for (int seg=0; seg<7; seg++){
    const float* src = (seg==0)?H0:(seg==1)?Hl1:(seg==2)?Hl2:(seg==3)?Hl3:(seg==4)?Hl4:feat;
    if (seg < 5){
      for (int t=tid; t<16*152; t+=256){
        int r=t/152, p=t-r*152, c=2*p;
        float v0 = (c<300)? src[(size_t)(r0+r)*300 + c] : 0.f;
        float v1 = (c+1<300)? src[(size_t)(r0+r)*300 + c+1] : 0.f;
        f16x2 h; h.x=(_Float16)v0; h.y=(_Float16)v1;
        Xh[r*256+p] = h;
      }
    } else {
      const int cb = (seg-5)*512;
      for (int t=tid; t<16*256; t+=256){
        int r=t>>8, p=t&255;
        float v0 = src[(size_t)(r0+r)*1024 + cb + 2*p];
        float v1 = src[(size_t)(r0+r)*1024 + cb + 2*p+1];
        f16x2 h; h.x=(_Float16)v0; h.y=(_Float16)v1;
        Xh[r*256+p] = h;
      }
    }
    __syncthreads();
    const int kgs = (seg<5)?38:64;
    const int kgo = (seg<5)? seg*38 : 190+(seg-5)*64;
    if (o < 300){
      for (int kg=0; kg<kgs; kg++){
        U a, b;
        a.u = W14u[(size_t)(kgo+kg)*304 + o];
        if (has2) b.u = W14u[(size_t)(kgo+kg)*304 + o2];
        #pragma unroll
        for (int r=0;r<16;r++){
          const f16x2* xp = &Xh[r*256 + kg*4];
          float t0 = fdot2a(a.h[0], xp[0], 0.f);
          t0 = fdot2a(a.h[1], xp[1], t0);
          t0 = fdot2a(a.h[2], xp[2], t0);
          t0 = fdot2a(a.h[3], xp[3], t0);
          acc0[r] += t0;
          if (has2){
            float t1 = fdot2a(b.h[0], xp[0], 0.f);
            t1 = fdot2a(b.h[1], xp[1], t1);
            t1 = fdot2a(b.h[2], xp[2], t1);
            t1 = fdot2a(b.h[3], xp[3], t1);
            acc1[r] += t1;
          }
        }
      }
    }
    __syncthreads();
  }
  if (o < 300){
    float bb = b1[o];
    #pragma unroll
    for (int r=0;r<16;r++) h1h[r*304+o] = (_Float16)fmaxf(acc0[r]+bb, 0.f);
  }
  if (has2){
    float bb = b1[o2];
    #pragma unroll
    for (int r=0;r<16;r++) h1h[r*304+o2] = (_Float16)fmaxf(acc1[r]+bb, 0.f);
  }
  if (tid < 4){
    #pragma unroll
    for (int r=0;r<16;r++) h1h[r*304+300+tid] = (_Float16)0.f;
  }
  __syncthreads();
  #pragma unroll
  for (int r=0;r<16;r++){ acc0[r]=0.f; acc1[r]=0.f; }
  if (o < 300){
    for (int kg=0; kg<38; kg++){
      U a, b;
      a.u = W24u[(size_t)kg*304 + o];
      if (has2) b.u = W24u[(size_t)kg*304 + o2];
      #pragma unroll
      for (int r=0;r<16;r++){
        const f16x2* xp = (const f16x2*)&h1h[r*304] + kg*4;
        float t0 = fdot2a(a.h[0], xp[0], 0.f);
        t0 = fdot2a(a.h[1], xp[1], t0);
        t0 = fdot2a(a.h[2], xp[2], t0);
        t0 = fdot2a(a.h[3], xp[3], t0);
        acc0[r] += t0;
        if (has2){
          float t1 = fdot2a(b.h[0], xp[0], 0.f);
          t1 = fdot2a(b.h[1], xp[1], t1);
          t1 = fdot2a(b.h[2], xp[2], t1);
          t1 = fdot2a(b.h[3], xp[3], t1);
          acc1[r] += t1;
        }
      }
    }
  }
  __syncthreads();
  if (o < 300){
    float bb = b2[o];
    #pragma unroll
    for (int r=0;r<16;r++) S2[r*304+o] = fmaxf(acc0[r]+bb, 0.f);
  }
  if (has2){
    float bb = b2[o2];
    #pragma unroll
    for (int r=0;r<16;r++) S2[r*304+o2] = fmaxf(acc1[r]+bb, 0.f);
  }
  __syncthreads();
  if (tid < 16*7){
    int r = tid/7, c = tid - r*7;
    float s = b3[c];
    const float* wrow = w3 + (size_t)c*HID;
    for (int k=0;k<300;k++) s += wrow[k]*S2[r*304+k];
    out[(size_t)(r0+r)*7 + c] = s;
  }
}

// ---------------------------------------------------------------------------
extern "C" void kernel_launch(void* const* d_in, const int* in_sizes, int n_in,
                              void* d_out, int out_size, void* d_ws, size_t ws_size,
                              hipStream_t stream)
{
  (void)in_sizes; (void)n_in; (void)out_size; (void)ws_size;
  const float* feat  = (const float*)d_in[0];
  const int*   spk   = (const int*)d_in[1];
  const float* w_in  = (const float*)d_in[2];
  const float* b_in  = (const float*)d_in[3];
  const float* gwq   = (const float*)d_in[4];
  const float* gwk   = (const float*)d_in[5];
  const float* gb    = (const float*)d_in[6];
  const float* wr0   = (const float*)d_in[7];
  const float* wr1   = (const float*)d_in[8];
  const float* wih_c = (const float*)d_in[9];
  const float* whh_c = (const float*)d_in[10];
  const float* bih_c = (const float*)d_in[11];
  const float* bhh_c = (const float*)d_in[12];
  const float* wih_p = (const float*)d_in[13];
  const float* whh_p = (const float*)d_in[14];
  const float* bih_p = (const float*)d_in[15];
  const float* bhh_p = (const float*)d_in[16];
  const float* w1    = (const float*)d_in[17];
  const float* b1    = (const float*)d_in[18];
  const float* w2    = (const float*)d_in[19];
  const float* b2    = (const float*)d_in[20];
  const float* w3    = (const float*)d_in[21];
  const float* b3    = (const float*)d_in[22];
  float* out = (float*)d_out;

  char* ws = (char*)d_ws;
  size_t off = 0;
  auto alloc = [&](size_t bytes)->void*{
    void* p = ws + off;
    off += (bytes + 255) & ~(size_t)255;
    return p;
  };
  f16x2* W_M4 = (f16x2*)alloc((size_t)4*38*1800*4 * sizeof(f16x2));
  f16x2* WrT4 = (f16x2*)alloc((size_t)4*38*600*4  * sizeof(f16x2));
  f16x2* W_P4 = (f16x2*)alloc((size_t)4*38*1800*4 * sizeof(f16x2));
  f16x2* W_H4 = (f16x2*)alloc((size_t)128*300*4   * sizeof(f16x2));
  f16x2* W_14 = (f16x2*)alloc((size_t)318*304*4   * sizeof(f16x2));
  f16x2* W_24 = (f16x2*)alloc((size_t)38*304*4    * sizeof(f16x2));
  float* Hball = (float*)alloc((size_t)5*NROWS*HID*sizeof(float));
  float* xrow  = (float*)alloc((size_t)3*64*NSEQ*HID*sizeof(float));
  int*   syncc = (int*)alloc((size_t)NSYNC*sizeof(int));
  float* xhEx  = (float*)alloc((size_t)128*2*600*sizeof(float));

  {
    const int tot = 4*38*1800*4 + 4*38*600*4 + 4*38*1800*4 + 128*300*4
                  + 318*304*4 + 38*304*4 + NSYNC;
    convert_all_kernel<<<(tot+255)/256, 256, 0, stream>>>(whh_c, wih_p, wih_c, whh_p,
        wr0, wr1, w_in, w1, w2, W_M4, WrT4, W_P4, W_H4, W_14, W_24, syncc);
  }
  h0_kernel<<<NROWS/8, 256, 0, stream>>>(feat, W_H4, b_in, Hball);

  scan_pipe_kernel<<<256, 1024, 0, stream>>>(Hball, W_M4, WrT4, W_P4,
      bih_c, bhh_c, bih_p, bhh_p, gwq, gwk, gb, spk, xrow, syncc, xhEx);

  head_kernel<<<NROWS/16, 256, 0, stream>>>(
      Hball, Hball + (size_t)NROWS*HID, Hball + (size_t)2*NROWS*HID,
      Hball + (size_t)3*NROWS*HID, Hball + (size_t)4*NROWS*HID,
      feat, W_14, b1, W_24, b2, w3, b3, out);
}

// Round 5
// 1744.446 us; speedup vs baseline: 1.6159x; 1.0272x over previous
//
#include <hip/hip_runtime.h>
#include <hip/hip_bf16.h>

typedef _Float16 f16x2 __attribute__((ext_vector_type(2)));

#define HID 300
#define NSEQ 64
#define NROWS 4096   // B*N = 64*64

union U { uint4 u; f16x2 h[4]; };

__device__ __forceinline__ float sigm(float x){ return 1.f/(1.f+__expf(-x)); }

__device__ __forceinline__ float fdot2a(f16x2 a, f16x2 b, float c){
#if __has_builtin(__builtin_amdgcn_fdot2)
  return __builtin_amdgcn_fdot2(a, b, c, false);
#else
  return c + (float)a.x*(float)b.x + (float)a.y*(float)b.y;
#endif
}

// Relaxed agent-scope ops: LLC-coherent, NO cache maintenance (no L2 flush).
__device__ __forceinline__ void xstore(float* p, float v){
  __hip_atomic_store(p, v, __ATOMIC_RELAXED, __HIP_MEMORY_SCOPE_AGENT);
}
__device__ __forceinline__ float xload(const float* p){
  return __hip_atomic_load(p, __ATOMIC_RELAXED, __HIP_MEMORY_SCOPE_AGENT);
}
__device__ __forceinline__ int xloadi(const int* p){
  return __hip_atomic_load(p, __ATOMIC_RELAXED, __HIP_MEMORY_SCOPE_AGENT);
}

// sync area layout (ints):
//   [0, 1536)            : cross-layer step counters (3 layers x 32 pairs x 16)
//   [1536, 1536+4096)    : fE flags (h-exchange, 128 pairs x 2 halves x 16)
//   [13824, 13824+64)    : claim pools (4 layers x 16)   (gap kept zeroed)
#define NSYNC (3*32*16 + 3*128*2*16 + 64)

// ---------------------------------------------------------------------------
// Merged repack: f32 -> fp16 pairs, [kg][outs][4 pairs] coalesced; also zeroes
// the pipeline sync counters + claim pools every launch.
// ---------------------------------------------------------------------------
__global__ void convert_all_kernel(
    const float* __restrict__ whh_c, const float* __restrict__ wih_p,
    const float* __restrict__ wih_c, const float* __restrict__ whh_p,
    const float* __restrict__ wr0,   const float* __restrict__ wr1,
    const float* __restrict__ w_in,  const float* __restrict__ w1,
    const float* __restrict__ w2,
    f16x2* __restrict__ W_M4, f16x2* __restrict__ WrT4, f16x2* __restrict__ W_P4,
    f16x2* __restrict__ W_H4, f16x2* __restrict__ W_14, f16x2* __restrict__ W_24,
    int* __restrict__ syncc)
{
  const int NA = 4*38*1800*4;
  const int NB = 4*38*600*4;
  const int NP = 4*38*1800*4;
  const int NH = 128*300*4;
  const int N1 = 318*304*4;
  const int N2 = 38*304*4;
  const int NS = NSYNC;
  const int TOT = NA+NB+NP+NH+N1+N2+NS;
  for (int idx0 = blockIdx.x*blockDim.x + threadIdx.x; idx0 < TOT; idx0 += gridDim.x*blockDim.x){
    int idx = idx0;
    if (idx < NA){
      int l    = idx/(38*1800*4);
      int rem  = idx - l*(38*1800*4);
      int kg   = rem/(1800*4);
      int rem2 = rem - kg*(1800*4);
      int o = rem2>>2, s = rem2&3;
      int c = (kg*4+s)*2;
      float v0=0.f, v1=0.f;
      if (c < 300){
        const float* src = (o<900) ? (whh_c + ((size_t)l*900+o)*300)
                                   : (wih_p + ((size_t)l*900+(o-900))*300);
        v0 = src[c]; v1 = src[c+1];
      }
      f16x2 t; t.x=(_Float16)v0; t.y=(_Float16)v1;
      W_M4[idx] = t; continue;
    }
    idx -= NA;
    if (idx < NB){
      int l    = idx/(38*600*4);
      int rem  = idx - l*(38*600*4);
      int kg   = rem/(600*4);
      int rem2 = rem - kg*(600*4);
      int t6 = rem2>>2, s = rem2&3;
      int d = t6>>1, hh = t6&1;
      int c = (kg*4+s)*2;
      float v0=0.f, v1=0.f;
      if (c < 300){
        const float* src = hh ? (wr1 + ((size_t)l*300+d)*300)
                              : (wr0 + ((size_t)l*300+d)*300);
        v0 = src[c]; v1 = src[c+1];
      }
      f16x2 t; t.x=(_Float16)v0; t.y=(_Float16)v1;
      WrT4[idx] = t; continue;
    }
    idx -= NB;
    if (idx < NP){
      int l    = idx/(38*1800*4);
      int rem  = idx - l*(38*1800*4);
      int kg   = rem/(1800*4);
      int rem2 = rem - kg*(1800*4);
      int o = rem2>>2, s = rem2&3;
      int c = (kg*4+s)*2;
      float v0=0.f, v1=0.f;
      if (c < 300){
        const float* src = (o<900) ? (wih_c + ((size_t)l*900+o)*300)
                                   : (whh_p + ((size_t)l*900+(o-900))*300);
        v0 = src[c]; v1 = src[c+1];
      }
      f16x2 t; t.x=(_Float16)v0; t.y=(_Float16)v1;
      W_P4[idx] = t; continue;
    }
    idx -= NP;
    if (idx < NH){
      int kg  = idx/(300*4);
      int rem = idx - kg*(300*4);
      int o = rem>>2, s = rem&3;
      int c = (kg*4+s)*2;
      f16x2 t; t.x=(_Float16)w_in[(size_t)o*1024+c]; t.y=(_Float16)w_in[(size_t)o*1024+c+1];
      W_H4[idx] = t; continue;
    }
    idx -= NH;
    if (idx < N1){
      int kgg = idx/(304*4);
      int rem = idx - kgg*(304*4);
      int o = rem>>2, s = rem&3;
      int segbase, seglen, kgl;
      if (kgg < 190){ int seg = kgg/38; kgl = kgg - seg*38; segbase = seg*300; seglen = 300; }
      else { int kk = kgg-190; int sf = kk>>6; kgl = kk&63; segbase = 1500 + sf*512; seglen = 512; }
      int c = (kgl*4+s)*2;
      float v0=0.f, v1=0.f;
      if (o < 300 && c < seglen){
        v0 = w1[(size_t)o*2524 + segbase + c];
        if (c+1 < seglen) v1 = w1[(size_t)o*2524 + segbase + c + 1];
      }
      f16x2 t; t.x=(_Float16)v0; t.y=(_Float16)v1;
      W_14[idx] = t; continue;
    }
    idx -= N1;
    if (idx < N2){
      int kg = idx/(304*4);
      int rem = idx - kg*(304*4);
      int o = rem>>2, s = rem&3;
      int c = (kg*4+s)*2;
      float v0=0.f, v1=0.f;
      if (o < 300 && c < 300){ v0 = w2[(size_t)o*300+c]; v1 = w2[(size_t)o*300+c+1]; }
      f16x2 t; t.x=(_Float16)v0; t.y=(_Float16)v1;
      W_24[idx] = t; continue;
    }
    idx -= N2;
    syncc[idx] = 0;
  }
}

// ---------------------------------------------------------------------------
// H0 = relu(features @ w_in^T + b_in), coalesced fp16 weights.
// ---------------------------------------------------------------------------
__global__ __launch_bounds__(256) void h0_kernel(const float* __restrict__ feat,
    const f16x2* __restrict__ WH, const float* __restrict__ b_in, float* __restrict__ H0)
{
  const int tid = threadIdx.x;
  const int r0  = blockIdx.x*8;
  __shared__ f16x2 X[8][512];
  for (int t=tid; t<8*512; t+=256){
    int r=t>>9, p=t&511, c=2*p;
    f16x2 h; h.x=(_Float16)feat[(size_t)(r0+r)*1024+c];
    h.y=(_Float16)feat[(size_t)(r0+r)*1024+c+1];
    X[r][p]=h;
  }
  __syncthreads();
  const uint4* WHu = (const uint4*)WH;
  const int o0 = tid, o1 = tid+256;
  const bool h1v = (o1 < 300);
  float acc[2][8];
  #pragma unroll
  for (int j=0;j<2;j++)
    #pragma unroll
    for (int r=0;r<8;r++) acc[j][r]=0.f;
  for (int kg=0; kg<128; kg++){
    U w0, w1;
    w0.u = WHu[(size_t)kg*300 + o0];
    if (h1v) w1.u = WHu[(size_t)kg*300 + o1];
    #pragma unroll
    for (int r=0;r<8;r++){
      const f16x2* xp = &X[r][kg*4];
      f16x2 x0=xp[0],x1=xp[1],x2=xp[2],x3=xp[3];
      acc[0][r] = fdot2a(w0.h[3],x3, fdot2a(w0.h[2],x2, fdot2a(w0.h[1],x1, fdot2a(w0.h[0],x0, acc[0][r]))));
      if (h1v)
        acc[1][r] = fdot2a(w1.h[3],x3, fdot2a(w1.h[2],x2, fdot2a(w1.h[1],x1, fdot2a(w1.h[0],x0, acc[1][r]))));
    }
  }
  {
    float bb = b_in[o0];
    #pragma unroll
    for (int r=0;r<8;r++) H0[(size_t)(r0+r)*HID + o0] = fmaxf(acc[0][r]+bb, 0.f);
  }
  if (h1v){
    float bb = b_in[o1];
    #pragma unroll
    for (int r=0;r<8;r++) H0[(size_t)(r0+r)*HID + o1] = fmaxf(acc[1][r]+bb, 0.f);
  }
}

// ---------------------------------------------------------------------------
// Fused 4-layer pipelined scan, d-SPLIT paired WGs: 256 WGs = 4 layers x
// 32 pairs x 2 halves. Half h owns gate-column range d in [150h,150h+150).
// This round: the {poll, partner-h import, kd reduce, softmax} chain runs on
// waves 0 and 8 ONLY (one chain per wave, fully in-wave), CONCURRENT with the
// P weight stream on waves 1-7/9-15 (896 threads cover P rows 0-895; wave 0
// lanes 0-3 mop up rows 896-899 after softmax). Barriers/step: 10 -> 7.
// ---------------------------------------------------------------------------
__global__ __launch_bounds__(1024) void scan_pipe_kernel(
  float* __restrict__ Hball,
  const f16x2* __restrict__ W_M4, const f16x2* __restrict__ WrT4, const f16x2* __restrict__ W_P4,
  const float* __restrict__ bih_c, const float* __restrict__ bhh_c,
  const float* __restrict__ bih_p, const float* __restrict__ bhh_p,
  const float* __restrict__ gwq, const float* __restrict__ gwk, const float* __restrict__ gbv,
  const int* __restrict__ speakers, float* __restrict__ xrow, int* __restrict__ syncc,
  float* __restrict__ xhEx)
{
  (void)gwq; (void)gbv;   // softmax is shift-invariant: q and b cancel exactly
  __shared__ _Float16 Hh[2][NSEQ][304];
  __shared__ float pre_s[2][1800];
  __shared__ float gates[2][1800];
  __shared__ float Mf[2][304];
  __shared__ f16x2 Mh[2][152];
  __shared__ f16x2 u01h[2][304];
  __shared__ float wgt[2][NSEQ];
  __shared__ float kd[2][NSEQ];
  __shared__ float red[2][320];
  __shared__ float xf[2][304];
  __shared__ f16x2 xh[2][152];
  __shared__ int   spk[2][NSEQ];
  __shared__ int   startA[2][NSEQ];
  __shared__ int   sLayer, sPair, sHalf;

  const int tid = threadIdx.x;

  // --- claim (layer, pair, half) with XCD-local preference; 64 slots/layer ---
  if (tid == 0){
    int xcc = 0;
    asm volatile("s_getreg_b32 %0, hwreg(HW_REG_XCC_ID)" : "=s"(xcc));
    int pref = (xcc >> 1) & 3;
    int* claimc = syncc + 3*32*16 + 3*128*2*16;
    int l = 0, p = 0, hf = 0;
    #pragma unroll 1
    for (int t=0; t<4; ++t){
      int cand = (pref + t) & 3;
      int idx = __hip_atomic_fetch_add(&claimc[cand*16], 1, __ATOMIC_RELAXED, __HIP_MEMORY_SCOPE_AGENT);
      if (idx < 64){ l = cand; p = idx>>1; hf = idx&1; break; }
    }
    sLayer = l; sPair = p; sHalf = hf;
  }
  __syncthreads();
  const int layer = sLayer;
  const int pair  = sPair;
  const int hf    = sHalf;
  const int base0 = (2*pair)*NSEQ;
  const int base1 = (2*pair+1)*NSEQ;

  const uint4* Wm4 = (const uint4*)(W_M4 + (size_t)layer*38*1800*4);
  const uint4* Wr4 = (const uint4*)(WrT4 + (size_t)layer*38*600*4);
  const uint4* Wp4 = (const uint4*)(W_P4 + (size_t)layer*38*1800*4);
  const float* HinB0 = Hball + (size_t)base0*300;
  const float* HinB1 = Hball + (size_t)base1*300;
  float* HoutB0 = Hball + ((size_t)(layer+1)*NROWS + (size_t)base0)*300;
  float* HoutB1 = Hball + ((size_t)(layer+1)*NROWS + (size_t)base1)*300;
  int* cntP = syncc + (layer*32 + pair)*16;
  int* cntC = (layer>0) ? (syncc + ((layer-1)*32 + pair)*16) : (int*)0;
  const float* xin  = xrow + (size_t)(((layer-1)*32 + pair)*2)*NSEQ*300;  // layer>0
  float*       xout = xrow + (size_t)((layer*32 + pair)*2)*NSEQ*300;      // layer<3

  // h-exchange pointers: per half, 2 parity slots x (2 chains x 150) f32
  const int lp = layer*32 + pair;
  float* xhMy = xhEx + ((size_t)lp*2 + hf)*600;
  const float* xhPt = xhEx + ((size_t)lp*2 + (1-hf))*600;
  int* fEmy = syncc + 1536 + (lp*2 + hf)*16;
  const int* fEpt = syncc + 1536 + (lp*2 + (1-hf))*16;

  const int w    = tid >> 6;   // wave id 0..15
  const int rc   = tid >> 9;   // half 0/1 (chain for R/E phases)
  const int rt   = tid & 511;
  const int lane = tid & 63;

  // E-phase per-thread regs (my d-range: d = hf*150 + rt, rt<150)
  float bcr=0,bcz=0,bcn=0,bpr=0,bpz=0,bpn=0,wkv=0;
  if (rt < 150){
    const int de = hf*150 + rt;
    bcr=bhh_c[layer*900+de]; bcz=bhh_c[layer*900+300+de]; bcn=bhh_c[layer*900+600+de];
    bpr=bih_p[layer*900+de]; bpz=bih_p[layer*900+300+de]; bpn=bih_p[layer*900+600+de];
    wkv=gwk[layer*300+de];
  }
  // import regs for waves 0/8: partner gwk values, 3 per lane
  float wkp0=0, wkp1=0, wkp2=0;
  if (w==0 || w==8){
    const int pbase = layer*300 + (1-hf)*150;
    wkp0 = gwk[pbase + lane];
    wkp1 = gwk[pbase + 64 + lane];
    if (lane < 22) wkp2 = gwk[pbase + 128 + lane];
  }

  // P mapping: waves 1-7,9-15 -> pidx 0..895 -> row rr=pidx; wave0 lanes 0-3 rows 896-899
  const bool isP = (w != 0) && (w != 8);
  int opmP = 0; float ppbP = 0.f;
  if (isP){
    const int pidx = (tid < 512) ? (tid - 64) : (tid - 128);   // 0..895
    const int g = pidx/150;
    const int dd = pidx - g*150;
    opmP = g*300 + hf*150 + dd;
    ppbP = (opmP<900) ? bih_c[layer*900+opmP] : bhh_p[layer*900+(opmP-900)];
  }
  int opmX = 0; float ppbX = 0.f;
  if (w==0 && lane<4){
    const int rr = 896 + lane;           // g=5, dd=rr-750
    opmX = 1500 + hf*150 + (rr - 750);
    ppbX = (opmX<900) ? bih_c[layer*900+opmX] : bhh_p[layer*900+(opmX-900)];
  }

  // D output mapping: tid<900 -> opm = (tid/150)*300 + hf*150 + tid%150
  int opm = 0;
  if (tid < 900){
    const int g = tid/150;
    const int dd = tid - g*150;
    opm = g*300 + hf*150 + dd;
  }

  // init
  if (tid < 64) spk[0][tid] = speakers[base0+tid];
  else if (tid < 128) spk[1][tid-64] = speakers[base1+(tid-64)];
  for (int t=tid; t<2*1800; t+=1024) ((float*)gates)[t]=0.f;
  for (int t=tid; t<2*304; t+=1024) ((float*)Mf)[t]=0.f;
  if (tid >= 128 && tid < 168){ int t=tid-128; red[t/20][300+(t%20)] = 0.f; }
  if (tid >= 168 && tid < 176){ int t=tid-168; xf[t>>2][300+(t&3)] = 0.f; }
  if (tid >= 176 && tid < 180){
    int t=tid-176; f16x2 z; z.x=(_Float16)0.f; z.y=(_Float16)0.f;
    Mh[t>>1][150+(t&1)]=z; xh[t>>1][150+(t&1)]=z;
    u01h[t>>1][150+(t&1)]=z; u01h[t>>1][302+(t&1)]=z;
  }
  __syncthreads();
  if (tid < 64){
    int s=0; for (int j=tid-1;j>=0;--j) if (spk[0][j]==spk[0][tid]){s=j;break;}
    startA[0][tid]=s;
  } else if (tid < 128){
    int t=tid-64;
    int s=0; for (int j=t-1;j>=0;--j) if (spk[1][j]==spk[1][t]){s=j;break;}
    startA[1][t]=s;
  }
  if (layer>0 && tid==0){
    while (xloadi(cntC) < 2) __builtin_amdgcn_s_sleep(8);   // row 0: both halves
  }
  __syncthreads();

  for (int i=0; i<NSEQ; ++i){
    // R: receive/load input row i for both chains (full 300 per chain)
    if (rt < 150){
      float x0, x1;
      if (layer==0){
        const float* Hin = rc ? HinB1 : HinB0;
        float2 v = *(const float2*)(Hin + (size_t)i*300 + 2*rt);
        x0=v.x; x1=v.y;
      } else {
        const float* xi = xin + (size_t)rc*NSEQ*300 + (size_t)i*300;
        x0 = xload(xi + 2*rt);
        x1 = xload(xi + 2*rt + 1);
      }
      xf[rc][2*rt]=x0; xf[rc][2*rt+1]=x1;
      f16x2 h; h.x=(_Float16)x0; h.y=(_Float16)x1; xh[rc][rt]=h;
    }
    __syncthreads();                                        // (1)

    // {P weight stream on waves 1-7,9-15}  ||  {poll+import+kd+softmax on waves 0,8}
    if (isP){
      float aA0=0,aA1=0,aA2=0,aA3=0, aB0=0,aB1=0,aB2=0,aB3=0;
      for (int kg=0;kg<38;kg++){
        U v; v.u = Wp4[(size_t)kg*1800 + opmP];
        f16x2 xA0=xh[0][kg*4+0],xA1=xh[0][kg*4+1],xA2=xh[0][kg*4+2],xA3=xh[0][kg*4+3];
        f16x2 xB0=xh[1][kg*4+0],xB1=xh[1][kg*4+1],xB2=xh[1][kg*4+2],xB3=xh[1][kg*4+3];
        aA0=fdot2a(v.h[0],xA0,aA0); aA1=fdot2a(v.h[1],xA1,aA1);
        aA2=fdot2a(v.h[2],xA2,aA2); aA3=fdot2a(v.h[3],xA3,aA3);
        aB0=fdot2a(v.h[0],xB0,aB0); aB1=fdot2a(v.h[1],xB1,aB1);
        aB2=fdot2a(v.h[2],xB2,aB2); aB3=fdot2a(v.h[3],xB3,aB3);
      }
      pre_s[0][opmP] = (aA0+aA1)+(aA2+aA3) + ppbP;
      pre_s[1][opmP] = (aB0+aB1)+(aB2+aB3) + ppbP;
    } else if (i > 0){
      const int c = (w==8);
      // poll partner E(i-1) completion (uniform branch, broadcast load)
      while (xloadi(fEpt) < i) __builtin_amdgcn_s_sleep(1);
      // import partner h(i-1): 150 values, 3 per lane
      const int par = ((i-1)&1)*300 + c*150;
      const int pb = (1-hf)*150;
      float hv0 = xload(xhPt + par + lane);
      float hv1 = xload(xhPt + par + 64 + lane);
      float hv2 = (lane<22) ? xload(xhPt + par + 128 + lane) : 0.f;
      red[c][pb+lane] = hv0*wkp0;      Hh[c][i-1][pb+lane] = (_Float16)hv0;
      red[c][pb+64+lane] = hv1*wkp1;   Hh[c][i-1][pb+64+lane] = (_Float16)hv1;
      if (lane<22){ red[c][pb+128+lane] = hv2*wkp2; Hh[c][i-1][pb+128+lane] = (_Float16)hv2; }
      // kd[c][i-1] reduce + softmax -> wgt for this step's B (all in-wave)
      float s = red[c][lane]+red[c][lane+64]+red[c][lane+128]+red[c][lane+192]+red[c][lane+256];
      #pragma unroll
      for (int o=32;o>0;o>>=1) s += __shfl_xor(s,o);
      if (lane==0) kd[c][i-1]=s;
      {
        const int st = startA[c][i];
        const bool in = (lane>=st) && (lane<i);
        float kv = (lane==i-1) ? s : kd[c][lane];
        float a = in ? kv : -3.0e38f;
        float m = a;
        #pragma unroll
        for (int o=32;o>0;o>>=1) m = fmaxf(m,__shfl_xor(m,o));
        float e = in ? __expf(a-m) : 0.f;
        float ss = e;
        #pragma unroll
        for (int o=32;o>0;o>>=1) ss += __shfl_xor(ss,o);
        wgt[c][lane] = e/ss;
      }
    }
    // wave 0 lanes 0-3: P rows 896-899 (after import/softmax; idle lanes otherwise)
    if (w==0 && lane<4){
      float aA0=0,aA1=0,aA2=0,aA3=0, aB0=0,aB1=0,aB2=0,aB3=0;
      for (int kg=0;kg<38;kg++){
        U v; v.u = Wp4[(size_t)kg*1800 + opmX];
        f16x2 xA0=xh[0][kg*4+0],xA1=xh[0][kg*4+1],xA2=xh[0][kg*4+2],xA3=xh[0][kg*4+3];
        f16x2 xB0=xh[1][kg*4+0],xB1=xh[1][kg*4+1],xB2=xh[1][kg*4+2],xB3=xh[1][kg*4+3];
        aA0=fdot2a(v.h[0],xA0,aA0); aA1=fdot2a(v.h[1],xA1,aA1);
        aA2=fdot2a(v.h[2],xA2,aA2); aA3=fdot2a(v.h[3],xA3,aA3);
        aB0=fdot2a(v.h[0],xB0,aB0); aB1=fdot2a(v.h[1],xB1,aB1);
        aB2=fdot2a(v.h[2],xB2,aB2); aB3=fdot2a(v.h[3],xB3,aB3);
      }
      pre_s[0][opmX] = (aA0+aA1)+(aA2+aA3) + ppbX;
      pre_s[1][opmX] = (aB0+aB1)+(aB2+aB3) + ppbX;
    }
    __syncthreads();                                        // (2)

    if (i > 0){
      // B: weighted history sums, full 1200 tasks (needs full Hh)
      #pragma unroll 1
      for (int pass=0; pass<2; ++pass){
        int T = tid + pass*1024;
        if (T < 1200){
          const int c = (T >= 600);
          const int t = T - c*600;
          const int d  = (t<300)? t : (t-300);
          const int wh = (t>=300);
          const int st = startA[c][i]; const int ms = spk[c][i];
          float u=0.f;
          for (int j=st;j<i;++j){
            float sel = ((spk[c][j]==ms) != (wh!=0)) ? 1.f : 0.f;
            u += sel*wgt[c][j]*(float)Hh[c][j][d];
          }
          ((_Float16*)&u01h[c][0])[(wh?304:0) + d] = (_Float16)u;
        }
      }
      __syncthreads();                                      // (3)
      // C: M = wr0@u0 + wr1@u1 — FULL redundant (M then local for D and E)
      if (tid < 600){
        const int hh = tid&1;
        const f16x2* uA = (const f16x2*)&u01h[0][0] + hh*152;
        const f16x2* uB = (const f16x2*)&u01h[1][0] + hh*152;
        float a0=0,a1=0,a2=0,a3=0, b0=0,b1=0,b2=0,b3=0;
        for (int kg=0;kg<38;kg++){
          U v; v.u = Wr4[(size_t)kg*600 + tid];
          a0=fdot2a(v.h[0],uA[kg*4+0],a0); a1=fdot2a(v.h[1],uA[kg*4+1],a1);
          a2=fdot2a(v.h[2],uA[kg*4+2],a2); a3=fdot2a(v.h[3],uA[kg*4+3],a3);
          b0=fdot2a(v.h[0],uB[kg*4+0],b0); b1=fdot2a(v.h[1],uB[kg*4+1],b1);
          b2=fdot2a(v.h[2],uB[kg*4+2],b2); b3=fdot2a(v.h[3],uB[kg*4+3],b3);
        }
        float aA = (a0+a1)+(a2+a3);
        float aB = (b0+b1)+(b2+b3);
        float m2A = aA + __shfl_xor(aA,1);
        float m2B = aB + __shfl_xor(aB,1);
        if ((tid&1)==0){ Mf[0][tid>>1] = m2A; Mf[1][tid>>1] = m2B; }
        float moA = __shfl_xor(m2A,2);
        float moB = __shfl_xor(m2B,2);
        if ((tid&3)==0){
          f16x2 hA; hA.x=(_Float16)m2A; hA.y=(_Float16)moA; Mh[0][tid>>2]=hA;
          f16x2 hB; hB.x=(_Float16)m2B; hB.y=(_Float16)moB; Mh[1][tid>>2]=hB;
        }
      }
      __syncthreads();                                      // (4)
      // D: gates = [whh_c ; wih_p] @ M — my 900 d-split rows
      if (tid < 900){
        float aA0=0,aA1=0,aA2=0,aA3=0, aB0=0,aB1=0,aB2=0,aB3=0;
        for (int kg=0;kg<38;kg++){
          U v; v.u = Wm4[(size_t)kg*1800 + opm];
          f16x2 mA0=Mh[0][kg*4+0], mA1=Mh[0][kg*4+1], mA2=Mh[0][kg*4+2], mA3=Mh[0][kg*4+3];
          f16x2 mB0=Mh[1][kg*4+0], mB1=Mh[1][kg*4+1], mB2=Mh[1][kg*4+2], mB3=Mh[1][kg*4+3];
          aA0=fdot2a(v.h[0],mA0,aA0); aA1=fdot2a(v.h[1],mA1,aA1);
          aA2=fdot2a(v.h[2],mA2,aA2); aA3=fdot2a(v.h[3],mA3,aA3);
          aB0=fdot2a(v.h[0],mB0,aB0); aB1=fdot2a(v.h[1],mB1,aB1);
          aB2=fdot2a(v.h[2],mB2,aB2); aB3=fdot2a(v.h[3],mB3,aB3);
        }
        gates[0][opm] = (aA0+aA1)+(aA2+aA3);
        gates[1][opm] = (aB0+aB1)+(aB2+aB3);
      }
      __syncthreads();                                      // (5)
    }
    // E: GRU combine for my d-range only (pre_s/gates/Mf all local)
    if (rt < 150){
      const int de = hf*150 + rt;
      const float M = Mf[rc][de];
      const float* ps = pre_s[rc];
      const float* gs = gates[rc];
      float r  = sigm(ps[de] + gs[de] + bcr);
      float z  = sigm(ps[300+de] + gs[300+de] + bcz);
      float n  = tanhf(ps[600+de] + r*(gs[600+de]+bcn));
      float C  = (1.f-z)*n + z*M;
      float rp = sigm(gs[900+de]+bpr + ps[900+de]);
      float zp = sigm(gs[1200+de]+bpz + ps[1200+de]);
      float np = tanhf(gs[1500+de]+bpn + rp*ps[1500+de]);
      float qv = xf[rc][de];
      float P  = (1.f-zp)*np + zp*qv;
      float h  = C + P;
      Hh[rc][i][de] = (_Float16)h;
      red[rc][de] = h*wkv;
      float* Ho = rc ? HoutB1 : HoutB0;
      Ho[(size_t)i*300 + de] = h;
      xstore(xhMy + (i&1)*300 + rc*150 + rt, h);
      if (layer<3) xstore(xout + (size_t)rc*NSEQ*300 + (size_t)i*300 + de, h);
    }
    asm volatile("s_waitcnt vmcnt(0)" ::: "memory");   // drain publish before flags
    __syncthreads();                                        // (6)
    if (tid==0){
      __hip_atomic_fetch_add(fEmy, 1, __ATOMIC_RELAXED, __HIP_MEMORY_SCOPE_AGENT);
      if (layer<3) __hip_atomic_fetch_add(cntP, 1, __ATOMIC_RELAXED, __HIP_MEMORY_SCOPE_AGENT);
      if (layer>0 && i<63){
        while (xloadi(cntC) < 2*(i+2)) __builtin_amdgcn_s_sleep(8);
      }
    }
    __syncthreads();                                        // (7)
  }
}

// ---------------------------------------------------------------------------
// Head with fp16-dot2 GEMMs (unchanged).
// ---------------------------------------------------------------------------
__global__ __launch_bounds__(256) void head_kernel(
  const float* __restrict__ H0, const float* __restrict__ Hl1,
  const float* __restrict__ Hl2, const float* __restrict__ Hl3,
  const float* __restrict__ Hl4, const float* __restrict__ feat,
  const f16x2* __restrict__ W14, const float* __restrict__ b1,
  const f16x2* __restrict__ W24, const float* __restrict__ b2,
  const float* __restrict__ w3, const float* __restrict__ b3,
  float* __restrict__ out)
{
  const int tid = threadIdx.x;
  const int r0  = blockIdx.x*16;
  __shared__ f16x2 Xh[16*256];
  __shared__ _Float16 h1h[16*304];
  __shared__ float S2[16*304];
  const uint4* W14u = (const uint4*)W14;
  const uint4* W24u = (const uint4*)W24;

  float acc0[16], acc1[16];
  #pragma unroll
  for (int r=0;r<16;r++){ acc0[r]=0.f; acc1[r]=0.f; }
  const int o  = tid;
  const int o2 = tid + 256;
  const bool has2 = (o2 < 300);

  #pragma unroll
  for (int seg=0; seg<7; seg++){
    const float* src = (seg==0)?H0:(seg==1)?Hl1:(seg==2)?Hl2:(seg==3)?Hl3:(seg==4)?Hl4:feat;
    if (seg < 5){
      for (int t=tid; t<16*152; t+=256){
        int r=t/152, p=t-r*152, c=2*p;
        float v0 = (c<300)? src[(size_t)(r0+r)*300 + c] : 0.f;
        float v1 = (c+1<300)? src[(size_t)(r0+r)*300 + c+1] : 0.f;
        f16x2 h; h.x=(_Float16)v0; h.y=(_Float16)v1;
        Xh[r*256+p] = h;
      }
    } else {
      const int cb = (seg-5)*512;
      for (int t=tid; t<16*256; t+=256){
        int r=t>>8, p=t&255;
        float v0 = src[(size_t)(r0+r)*1024 + cb + 2*p];
        float v1 = src[(size_t)(r0+r)*1024 + cb + 2*p+1];
        f16x2 h; h.x=(_Float16)v0; h.y=(_Float16)v1;
        Xh[r*256+p] = h;
      }
    }
    __syncthreads();
    const int kgs = (seg<5)?38:64;
    const int kgo = (seg<5)? seg*38 : 190+(seg-5)*64;
    if (o < 300){
      for (int kg=0; kg<kgs; kg++){
        U a, b;
        a.u = W14u[(size_t)(kgo+kg)*304 + o];
        if (has2) b.u = W14u[(size_t)(kgo+kg)*304 + o2];
        #pragma unroll
        for (int r=0;r<16;r++){
          const f16x2* xp = &Xh[r*256 + kg*4];
          float t0 = fdot2a(a.h[0], xp[0], 0.f);
          t0 = fdot2a(a.h[1], xp[1], t0);
          t0 = fdot2a(a.h[2], xp[2], t0);
          t0 = fdot2a(a.h[3], xp[3], t0);
          acc0[r] += t0;
          if (has2){
            float t1 = fdot2a(b.h[0], xp[0], 0.f);
            t1 = fdot2a(b.h[1], xp[1], t1);
            t1 = fdot2a(b.h[2], xp[2], t1);
            t1 = fdot2a(b.h[3], xp[3], t1);
            acc1[r] += t1;
          }
        }
      }
    }
    __syncthreads();
  }
  if (o < 300){
    float bb = b1[o];
    #pragma unroll
    for (int r=0;r<16;r++) h1h[r*304+o] = (_Float16)fmaxf(acc0[r]+bb, 0.f);
  }
  if (has2){
    float bb = b1[o2];
    #pragma unroll
    for (int r=0;r<16;r++) h1h[r*304+o2] = (_Float16)fmaxf(acc1[r]+bb, 0.f);
  }
  if (tid < 4){
    #pragma unroll
    for (int r=0;r<16;r++) h1h[r*304+300+tid] = (_Float16)0.f;
  }
  __syncthreads();
  #pragma unroll
  for (int r=0;r<16;r++){ acc0[r]=0.f; acc1[r]=0.f; }
  if (o < 300){
    for (int kg=0; kg<38; kg++){
      U a, b;
      a.u = W24u[(size_t)kg*304 + o];
      if (has2) b.u = W24u[(size_t)kg*304 + o2];
      #pragma unroll
      for (int r=0;r<16;r++){
        const f16x2* xp = (const f16x2*)&h1h[r*304] + kg*4;
        float t0 = fdot2a(a.h[0], xp[0], 0.f);
        t0 = fdot2a(a.h[1], xp[1], t0);
        t0 = fdot2a(a.h[2], xp[2], t0);
        t0 = fdot2a(a.h[3], xp[3], t0);
        acc0[r] += t0;
        if (has2){
          float t1 = fdot2a(b.h[0], xp[0], 0.f);
          t1 = fdot2a(b.h[1], xp[1], t1);
          t1 = fdot2a(b.h[2], xp[2], t1);
          t1 = fdot2a(b.h[3], xp[3], t1);
          acc1[r] += t1;
        }
      }
    }
  }
  __syncthreads();
  if (o < 300){
    float bb = b2[o];
    #pragma unroll
    for (int r=0;r<16;r++) S2[r*304+o] = fmaxf(acc0[r]+bb, 0.f);
  }
  if (has2){
    float bb = b2[o2];
    #pragma unroll
    for (int r=0;r<16;r++) S2[r*304+o2] = fmaxf(acc1[r]+bb, 0.f);
  }
  __syncthreads();
  if (tid < 16*7){
    int r = tid/7, c = tid - r*7;
    float s = b3[c];
    const float* wrow = w3 + (size_t)c*HID;
    for (int k=0;k<300;k++) s += wrow[k]*S2[r*304+k];
    out[(size_t)(r0+r)*7 + c] = s;
  }
}

// ---------------------------------------------------------------------------
extern "C" void kernel_launch(void* const* d_in, const int* in_sizes, int n_in,
                              void* d_out, int out_size, void* d_ws, size_t ws_size,
                              hipStream_t stream)
{
  (void)in_sizes; (void)n_in; (void)out_size; (void)ws_size;
  const float* feat  = (const float*)d_in[0];
  const int*   spk   = (const int*)d_in[1];
  const float* w_in  = (const float*)d_in[2];
  const float* b_in  = (const float*)d_in[3];
  const float* gwq   = (const float*)d_in[4];
  const float* gwk   = (const float*)d_in[5];
  const float* gb    = (const float*)d_in[6];
  const float* wr0   = (const float*)d_in[7];
  const float* wr1   = (const float*)d_in[8];
  const float* wih_c = (const float*)d_in[9];
  const float* whh_c = (const float*)d_in[10];
  const float* bih_c = (const float*)d_in[11];
  const float* bhh_c = (const float*)d_in[12];
  const float* wih_p = (const float*)d_in[13];
  const float* whh_p = (const float*)d_in[14];
  const float* bih_p = (const float*)d_in[15];
  const float* bhh_p = (const float*)d_in[16];
  const float* w1    = (const float*)d_in[17];
  const float* b1    = (const float*)d_in[18];
  const float* w2    = (const float*)d_in[19];
  const float* b2    = (const float*)d_in[20];
  const float* w3    = (const float*)d_in[21];
  const float* b3    = (const float*)d_in[22];
  float* out = (float*)d_out;

  char* ws = (char*)d_ws;
  size_t off = 0;
  auto alloc = [&](size_t bytes)->void*{
    void* p = ws + off;
    off += (bytes + 255) & ~(size_t)255;
    return p;
  };
  f16x2* W_M4 = (f16x2*)alloc((size_t)4*38*1800*4 * sizeof(f16x2));
  f16x2* WrT4 = (f16x2*)alloc((size_t)4*38*600*4  * sizeof(f16x2));
  f16x2* W_P4 = (f16x2*)alloc((size_t)4*38*1800*4 * sizeof(f16x2));
  f16x2* W_H4 = (f16x2*)alloc((size_t)128*300*4   * sizeof(f16x2));
  f16x2* W_14 = (f16x2*)alloc((size_t)318*304*4   * sizeof(f16x2));
  f16x2* W_24 = (f16x2*)alloc((size_t)38*304*4    * sizeof(f16x2));
  float* Hball = (float*)alloc((size_t)5*NROWS*HID*sizeof(float));
  float* xrow  = (float*)alloc((size_t)3*64*NSEQ*HID*sizeof(float));
  int*   syncc = (int*)alloc((size_t)NSYNC*sizeof(int));
  float* xhEx  = (float*)alloc((size_t)128*2*600*sizeof(float));

  {
    const int tot = 4*38*1800*4 + 4*38*600*4 + 4*38*1800*4 + 128*300*4
                  + 318*304*4 + 38*304*4 + NSYNC;
    convert_all_kernel<<<(tot+255)/256, 256, 0, stream>>>(whh_c, wih_p, wih_c, whh_p,
        wr0, wr1, w_in, w1, w2, W_M4, WrT4, W_P4, W_H4, W_14, W_24, syncc);
  }
  h0_kernel<<<NROWS/8, 256, 0, stream>>>(feat, W_H4, b_in, Hball);

  scan_pipe_kernel<<<256, 1024, 0, stream>>>(Hball, W_M4, WrT4, W_P4,
      bih_c, bhh_c, bih_p, bhh_p, gwq, gwk, gb, spk, xrow, syncc, xhEx);

  head_kernel<<<NROWS/16, 256, 0, stream>>>(
      Hball, Hball + (size_t)NROWS*HID, Hball + (size_t)2*NROWS*HID,
      Hball + (size_t)3*NROWS*HID, Hball + (size_t)4*NROWS*HID,
      feat, W_14, b1, W_24, b2, w3, b3, out);
}